// Round 5
// baseline (2477.988 us; speedup 1.0000x reference)
//
#include <hip/hip_runtime.h>
#include <math.h>

#define BATCH 128
#define T 250
#define D_IN 700
#define H 256
#define D_OUT 20
#define NW 4            // waves per recurrent block

// ---------------------------------------------------------------------------
// Workspace layout (fp32):
//   U     [32001][256]  (one pad row: u-prefetch overrun at t=249 of last block)
//   Wi1T  [705][256]    rows 700..704 zero (gemm K-pad + prefetch overrun row)
//   C1    [257][512]    row k, lane l: {W12T[k][4l..4l+3], W11T[k][4l..4l+3]}
//   C2    [257][512]    row k, lane l: {W22T[k][4l..4l+3], Wo[l&31][k], 0,0,0}
//   row 256 of C1/C2 is all-zero (spike-list padding target)
// ---------------------------------------------------------------------------
#define N_WI1T (705 * 256)
#define N_C    (257 * 512)

__global__ void prep_k(const float* __restrict__ Wi1, const float* __restrict__ W11,
                       const float* __restrict__ W12, const float* __restrict__ W22,
                       const float* __restrict__ Wo,
                       float* __restrict__ Wi1T, float* __restrict__ C1,
                       float* __restrict__ C2) {
    int idx = blockIdx.x * 256 + threadIdx.x;
    if (idx < N_WI1T) {
        int k = idx >> 8, h = idx & 255;
        Wi1T[idx] = (k < D_IN) ? Wi1[h * D_IN + k] : 0.f;
        return;
    }
    idx -= N_WI1T;
    if (idx < N_C) {
        int k = idx >> 9, q = idx & 511;
        int l = q >> 3, jj = q & 7;
        float v = 0.f;
        if (k < H) {
            int h = 4 * l + (jj & 3);
            v = (jj < 4) ? W12[h * H + k] : W11[h * H + k];
        }
        C1[idx] = v;
        return;
    }
    idx -= N_C;
    if (idx < N_C) {
        int k = idx >> 9, q = idx & 511;
        int l = q >> 3, jj = q & 7;
        float v = 0.f;
        if (k < H) {
            if (jj < 4) v = W22[(4 * l + jj) * H + k];
            else if (jj == 4 && (l & 31) < D_OUT) v = Wo[(l & 31) * H + k];
        }
        C2[idx] = v;
    }
}

// ---------------------------------------------------------------------------
// U = x @ Wi1^T + bi1.  64-row tile, 500 blocks (~2/CU), thread = 8 rows x 8 cols.
// ---------------------------------------------------------------------------
#define GR 64
#define GK 64
__global__ __launch_bounds__(256) void gemm_u_k(const float* __restrict__ x,
                                                const float* __restrict__ Wi1T,
                                                const float* __restrict__ bi1,
                                                float* __restrict__ U) {
    __shared__ float xs[GK][GR + 4];
    int tid = threadIdx.x;
    int c0 = (tid & 31) * 8;
    int r0 = (tid >> 5) * 8;
    int m0 = blockIdx.x * GR;

    float4 a0[8], a1[8];
#pragma unroll
    for (int r = 0; r < 8; ++r) {
        a0[r] = make_float4(0.f, 0.f, 0.f, 0.f);
        a1[r] = make_float4(0.f, 0.f, 0.f, 0.f);
    }

    for (int k0 = 0; k0 < 704; k0 += GK) {
        __syncthreads();
#pragma unroll
        for (int i = 0; i < 4; ++i) {
            int f = tid + (i << 8);
            int r = f >> 4, c4 = (f & 15) << 2;
            int k = k0 + c4;
            float4 v = make_float4(0.f, 0.f, 0.f, 0.f);
            if (k < D_IN) v = *(const float4*)(x + (size_t)(m0 + r) * D_IN + k);
            xs[c4 + 0][r] = v.x; xs[c4 + 1][r] = v.y;
            xs[c4 + 2][r] = v.z; xs[c4 + 3][r] = v.w;
        }
        __syncthreads();

        const float* wp = Wi1T + (size_t)k0 * H + c0;
        float4 w0 = *(const float4*)(wp);
        float4 w1 = *(const float4*)(wp + 4);
        for (int k = 0; k < GK; ++k) {
            const float* wn = Wi1T + (size_t)(k0 + k + 1) * H + c0;
            float4 nw0 = *(const float4*)(wn);
            float4 nw1 = *(const float4*)(wn + 4);
            float4 xa = *(const float4*)(&xs[k][r0]);
            float4 xb = *(const float4*)(&xs[k][r0 + 4]);
            float xv[8] = {xa.x, xa.y, xa.z, xa.w, xb.x, xb.y, xb.z, xb.w};
#pragma unroll
            for (int r = 0; r < 8; ++r) {
                float xr = xv[r];
                a0[r].x += xr * w0.x; a0[r].y += xr * w0.y;
                a0[r].z += xr * w0.z; a0[r].w += xr * w0.w;
                a1[r].x += xr * w1.x; a1[r].y += xr * w1.y;
                a1[r].z += xr * w1.z; a1[r].w += xr * w1.w;
            }
            w0 = nw0; w1 = nw1;
        }
    }

    float4 bb0 = *(const float4*)(bi1 + c0);
    float4 bb1 = *(const float4*)(bi1 + c0 + 4);
#pragma unroll
    for (int r = 0; r < 8; ++r) {
        float* up = U + (size_t)(m0 + r0 + r) * H + c0;
        float4 o0, o1;
        o0.x = a0[r].x + bb0.x; o0.y = a0[r].y + bb0.y;
        o0.z = a0[r].z + bb0.z; o0.w = a0[r].w + bb0.w;
        o1.x = a1[r].x + bb1.x; o1.y = a1[r].y + bb1.y;
        o1.z = a1[r].z + bb1.z; o1.w = a1[r].w + bb1.w;
        *(float4*)(up) = o0;
        *(float4*)(up + 4) = o1;
    }
}

// ---------------------------------------------------------------------------
// Recurrent: 4 waves/block, one block per batch element. Redundant state in
// all waves; gathers split 4 ways; depth-2 group ring (32 loads in flight);
// ONE barrier per step (double-buffered partials); softmax delayed one step.
// ---------------------------------------------------------------------------

__device__ __forceinline__ int build_list(unsigned int* list, int lane,
                                          float sx, float sy, float sz, float sw) {
    unsigned long long m0 = __ballot(sx > 0.f);
    unsigned long long m1 = __ballot(sy > 0.f);
    unsigned long long m2 = __ballot(sz > 0.f);
    unsigned long long m3 = __ballot(sw > 0.f);
    unsigned long long below = (1ull << lane) - 1ull;
    int c0 = __popcll(m0), c1 = __popcll(m1), c2 = __popcll(m2), c3 = __popcll(m3);
    int n = c0 + c1 + c2 + c3;
    if ((m0 >> lane) & 1) list[__popcll(m0 & below)] = lane * 4;
    if ((m1 >> lane) & 1) list[c0 + __popcll(m1 & below)] = lane * 4 + 1;
    if ((m2 >> lane) & 1) list[c0 + c1 + __popcll(m2 & below)] = lane * 4 + 2;
    if ((m3 >> lane) & 1) list[c0 + c1 + c2 + __popcll(m3 & below)] = lane * 4 + 3;
    list[n + lane] = 256;                   // 64 pads (zero weight row)
    __builtin_amdgcn_wave_barrier();
    return n;
}

// Depth-2 ring gather, dual float4 per row (C1: W12 at +l8, W11 at +l8+4).
// rows is a multiple of 8 (may be 0).
__device__ __forceinline__ void gather_dual(const unsigned int* lst, int rows,
                                            const float* __restrict__ C,
                                            unsigned l8, float4& A, float4& B) {
    int ng = rows >> 3;
    if (ng <= 0) return;
    float4 wa[2][8], wb[2][8];
#pragma unroll
    for (int j = 0; j < 8; ++j) {
        const float* p = C + (lst[j] << 9) + l8;
        wa[0][j] = *(const float4*)(p);
        wb[0][j] = *(const float4*)(p + 4);
    }
    if (ng > 1) {
#pragma unroll
        for (int j = 0; j < 8; ++j) {
            const float* p = C + (lst[8 + j] << 9) + l8;
            wa[1][j] = *(const float4*)(p);
            wb[1][j] = *(const float4*)(p + 4);
        }
    }
    for (int g = 0; g < ng; ++g) {
        int cur = g & 1;
#pragma unroll
        for (int j = 0; j < 8; ++j) {
            A.x += wa[cur][j].x; A.y += wa[cur][j].y;
            A.z += wa[cur][j].z; A.w += wa[cur][j].w;
            B.x += wb[cur][j].x; B.y += wb[cur][j].y;
            B.z += wb[cur][j].z; B.w += wb[cur][j].w;
        }
        int nxt = g + 2;
        if (nxt < ng) {
#pragma unroll
            for (int j = 0; j < 8; ++j) {
                const float* p = C + (lst[8 * nxt + j] << 9) + l8;
                wa[cur][j] = *(const float4*)(p);
                wb[cur][j] = *(const float4*)(p + 4);
            }
        }
    }
}

// Depth-2 ring gather, float4 + scalar per row (C2: W22 at +l8, Wo at +l8+4).
__device__ __forceinline__ void gather_fs(const unsigned int* lst, int rows,
                                          const float* __restrict__ C,
                                          unsigned l8, float4& A, float& O) {
    int ng = rows >> 3;
    if (ng <= 0) return;
    float4 wa[2][8]; float wo[2][8];
#pragma unroll
    for (int j = 0; j < 8; ++j) {
        const float* p = C + (lst[j] << 9) + l8;
        wa[0][j] = *(const float4*)(p);
        wo[0][j] = p[4];
    }
    if (ng > 1) {
#pragma unroll
        for (int j = 0; j < 8; ++j) {
            const float* p = C + (lst[8 + j] << 9) + l8;
            wa[1][j] = *(const float4*)(p);
            wo[1][j] = p[4];
        }
    }
    for (int g = 0; g < ng; ++g) {
        int cur = g & 1;
#pragma unroll
        for (int j = 0; j < 8; ++j) {
            A.x += wa[cur][j].x; A.y += wa[cur][j].y;
            A.z += wa[cur][j].z; A.w += wa[cur][j].w;
            O += wo[cur][j];
        }
        int nxt = g + 2;
        if (nxt < ng) {
#pragma unroll
            for (int j = 0; j < 8; ++j) {
                const float* p = C + (lst[8 * nxt + j] << 9) + l8;
                wa[cur][j] = *(const float4*)(p);
                wo[cur][j] = p[4];
            }
        }
    }
}

__global__ __launch_bounds__(256, 1) void recurrent_k(
    const float* __restrict__ U,
    const float* __restrict__ mem1_0, const float* __restrict__ mem2_0,
    const float* __restrict__ memo_0,
    const float* __restrict__ b11v, const float* __restrict__ b12v,
    const float* __restrict__ b22v, const float* __restrict__ bov,
    const float* __restrict__ tau_adp_h1, const float* __restrict__ tau_adp_h2,
    const float* __restrict__ tau_m_h1, const float* __restrict__ tau_m_h2,
    const float* __restrict__ tau_m_o,
    const float* __restrict__ C1, const float* __restrict__ C2,
    float* __restrict__ out)
{
    const int tid = threadIdx.x;
    const int lane = tid & 63;
    const int wv = tid >> 6;                 // 0..3
    const int bi = blockIdx.x;
    const unsigned laneOff = lane * 4;
    const unsigned l8 = lane * 8;

    __shared__ __align__(16) unsigned int list1[320], list2[320];
    __shared__ __align__(16) float p12[2][NW][H];
    __shared__ __align__(16) float p11[2][NW][H];
    __shared__ __align__(16) float p22[2][NW][H];
    __shared__ __align__(16) float pO[2][NW][64];

    for (int i = tid; i < NW * H; i += 256) {
        ((float*)p11[1])[i] = 0.f;
        ((float*)p22[1])[i] = 0.f;
    }
    __syncthreads();

    // ---- redundant per-lane state in all 4 waves: neurons h = lane*4 + j
    float4 mem1 = *(const float4*)(mem1_0 + bi * H + laneOff);
    float4 mem2 = *(const float4*)(mem2_0 + bi * H + laneOff);
    float4 b1 = make_float4(0.01f, 0.01f, 0.01f, 0.01f);
    float4 b2 = make_float4(0.01f, 0.01f, 0.01f, 0.01f);
    float4 spk1 = make_float4(0.f, 0.f, 0.f, 0.f);
    float4 spk2 = make_float4(0.f, 0.f, 0.f, 0.f);

    float4 tm1 = *(const float4*)(tau_m_h1 + laneOff);
    float4 ta1 = *(const float4*)(tau_adp_h1 + laneOff);
    float4 tm2 = *(const float4*)(tau_m_h2 + laneOff);
    float4 ta2 = *(const float4*)(tau_adp_h2 + laneOff);
    float4 al1, ro1, al2, ro2;
    al1.x = expf(-1.f / tm1.x); al1.y = expf(-1.f / tm1.y);
    al1.z = expf(-1.f / tm1.z); al1.w = expf(-1.f / tm1.w);
    ro1.x = expf(-1.f / ta1.x); ro1.y = expf(-1.f / ta1.y);
    ro1.z = expf(-1.f / ta1.z); ro1.w = expf(-1.f / ta1.w);
    al2.x = expf(-1.f / tm2.x); al2.y = expf(-1.f / tm2.y);
    al2.z = expf(-1.f / tm2.z); al2.w = expf(-1.f / tm2.w);
    ro2.x = expf(-1.f / ta2.x); ro2.y = expf(-1.f / ta2.y);
    ro2.z = expf(-1.f / ta2.z); ro2.w = expf(-1.f / ta2.w);
    float4 oma1, omr1, oma2, omr2;
    oma1.x = 1.f - al1.x; oma1.y = 1.f - al1.y; oma1.z = 1.f - al1.z; oma1.w = 1.f - al1.w;
    omr1.x = 1.f - ro1.x; omr1.y = 1.f - ro1.y; omr1.z = 1.f - ro1.z; omr1.w = 1.f - ro1.w;
    oma2.x = 1.f - al2.x; oma2.y = 1.f - al2.y; oma2.z = 1.f - al2.z; oma2.w = 1.f - al2.w;
    omr2.x = 1.f - ro2.x; omr2.y = 1.f - ro2.y; omr2.z = 1.f - ro2.z; omr2.w = 1.f - ro2.w;

    float4 b11r = *(const float4*)(b11v + laneOff);
    float4 b12r = *(const float4*)(b12v + laneOff);
    float4 b22r = *(const float4*)(b22v + laneOff);
    float4 bsum2;
    bsum2.x = b12r.x + b22r.x; bsum2.y = b12r.y + b22r.y;
    bsum2.z = b12r.z + b22r.z; bsum2.w = b12r.w + b22r.w;

    float memo = 0.f, alpha_o = 0.f, bo_r = 0.f, accv = 0.f;
    if (lane < D_OUT) {
        memo = memo_0[bi * D_OUT + lane];
        alpha_o = expf(-1.f / tau_m_o[lane]);
        bo_r = bov[lane];
    }

    const float* Up = U + (size_t)bi * T * H + laneOff;
    float4 u_cur = *(const float4*)(Up);

    for (int t = 0; t < T; ++t) {
        const int buf = t & 1, pb = buf ^ 1;

        // prefetch next step's u early (row t+1 exists: U has a pad row)
        float4 u_nxt = *(const float4*)(Up + H);
        Up += H;

        // ===== phase 1: g11 = W11@sp1(t-1); layer-1 update; list1; gather C1
        float4 g11;
        {
            float4 q0 = ((const float4*)p11[pb][0])[lane];
            float4 q1 = ((const float4*)p11[pb][1])[lane];
            float4 q2 = ((const float4*)p11[pb][2])[lane];
            float4 q3 = ((const float4*)p11[pb][3])[lane];
            g11.x = q0.x + q1.x + q2.x + q3.x; g11.y = q0.y + q1.y + q2.y + q3.y;
            g11.z = q0.z + q1.z + q2.z + q3.z; g11.w = q0.w + q1.w + q2.w + q3.w;
        }
        float4 h1;
        h1.x = u_cur.x + b11r.x + g11.x; h1.y = u_cur.y + b11r.y + g11.y;
        h1.z = u_cur.z + b11r.z + g11.z; h1.w = u_cur.w + b11r.w + g11.w;
        b1.x = ro1.x * b1.x + omr1.x * spk1.x; b1.y = ro1.y * b1.y + omr1.y * spk1.y;
        b1.z = ro1.z * b1.z + omr1.z * spk1.z; b1.w = ro1.w * b1.w + omr1.w * spk1.w;
        float B1x = 0.01f + 1.8f * b1.x, B1y = 0.01f + 1.8f * b1.y;
        float B1z = 0.01f + 1.8f * b1.z, B1w = 0.01f + 1.8f * b1.w;
        mem1.x = mem1.x * al1.x + oma1.x * h1.x - B1x * spk1.x;
        mem1.y = mem1.y * al1.y + oma1.y * h1.y - B1y * spk1.y;
        mem1.z = mem1.z * al1.z + oma1.z * h1.z - B1z * spk1.z;
        mem1.w = mem1.w * al1.w + oma1.w * h1.w - B1w * spk1.w;
        spk1.x = (mem1.x - B1x > 0.f) ? 1.f : 0.f;
        spk1.y = (mem1.y - B1y > 0.f) ? 1.f : 0.f;
        spk1.z = (mem1.z - B1z > 0.f) ? 1.f : 0.f;
        spk1.w = (mem1.w - B1w > 0.f) ? 1.f : 0.f;

        int n1 = build_list(list1, lane, spk1.x, spk1.y, spk1.z, spk1.w);
        int n1p = (n1 + 31) & ~31;
        int chunk1 = n1p >> 2;                  // per-wave rows, multiple of 8

        float4 a12 = make_float4(0.f, 0.f, 0.f, 0.f);
        float4 a11 = make_float4(0.f, 0.f, 0.f, 0.f);
        gather_dual(list1 + wv * chunk1, chunk1, C1, l8, a12, a11);
        ((float4*)p12[buf][wv])[lane] = a12;
        ((float4*)p11[buf][wv])[lane] = a11;
        __syncthreads();                        // THE barrier (1 per step)

        // ===== phase 2: combine g12 (this step) + g22 (carried); layer-2; list2
        float4 g12, g22;
        {
            float4 q0 = ((const float4*)p12[buf][0])[lane];
            float4 q1 = ((const float4*)p12[buf][1])[lane];
            float4 q2 = ((const float4*)p12[buf][2])[lane];
            float4 q3 = ((const float4*)p12[buf][3])[lane];
            g12.x = q0.x + q1.x + q2.x + q3.x; g12.y = q0.y + q1.y + q2.y + q3.y;
            g12.z = q0.z + q1.z + q2.z + q3.z; g12.w = q0.w + q1.w + q2.w + q3.w;
            float4 r0 = ((const float4*)p22[pb][0])[lane];
            float4 r1 = ((const float4*)p22[pb][1])[lane];
            float4 r2 = ((const float4*)p22[pb][2])[lane];
            float4 r3 = ((const float4*)p22[pb][3])[lane];
            g22.x = r0.x + r1.x + r2.x + r3.x; g22.y = r0.y + r1.y + r2.y + r3.y;
            g22.z = r0.z + r1.z + r2.z + r3.z; g22.w = r0.w + r1.w + r2.w + r3.w;
        }
        float4 h2;
        h2.x = bsum2.x + g22.x + g12.x; h2.y = bsum2.y + g22.y + g12.y;
        h2.z = bsum2.z + g22.z + g12.z; h2.w = bsum2.w + g22.w + g12.w;
        b2.x = ro2.x * b2.x + omr2.x * spk2.x; b2.y = ro2.y * b2.y + omr2.y * spk2.y;
        b2.z = ro2.z * b2.z + omr2.z * spk2.z; b2.w = ro2.w * b2.w + omr2.w * spk2.w;
        float B2x = 0.01f + 1.8f * b2.x, B2y = 0.01f + 1.8f * b2.y;
        float B2z = 0.01f + 1.8f * b2.z, B2w = 0.01f + 1.8f * b2.w;
        mem2.x = mem2.x * al2.x + oma2.x * h2.x - B2x * spk2.x;
        mem2.y = mem2.y * al2.y + oma2.y * h2.y - B2y * spk2.y;
        mem2.z = mem2.z * al2.z + oma2.z * h2.z - B2z * spk2.z;
        mem2.w = mem2.w * al2.w + oma2.w * h2.w - B2w * spk2.w;
        spk2.x = (mem2.x - B2x > 0.f) ? 1.f : 0.f;
        spk2.y = (mem2.y - B2y > 0.f) ? 1.f : 0.f;
        spk2.z = (mem2.z - B2z > 0.f) ? 1.f : 0.f;
        spk2.w = (mem2.w - B2w > 0.f) ? 1.f : 0.f;

        int n2 = build_list(list2, lane, spk2.x, spk2.y, spk2.z, spk2.w);
        int n2p = (n2 + 31) & ~31;
        int chunk2 = n2p >> 2;

        float4 a22 = make_float4(0.f, 0.f, 0.f, 0.f);
        float aO = 0.f;
        gather_fs(list2 + wv * chunk2, chunk2, C2, l8, a22, aO);

        // ---- delayed output/softmax: consume PREVIOUS step's Wo partials
        if (t >= 1) {
            float gO = pO[pb][0][lane] + pO[pb][1][lane]
                     + pO[pb][2][lane] + pO[pb][3][lane];
            float o = bo_r + gO;
            memo = memo * alpha_o + (1.f - alpha_o) * o;   // memo(t-1)
            if (t >= 12) {                                  // (t-1) > 10
                float e = (lane < D_OUT) ? __expf(memo) : 0.f;
                float s = e;
#pragma unroll
                for (int d = 16; d >= 1; d >>= 1) s += __shfl_xor(s, d, 32);
                if (lane < D_OUT) accv += __fdividef(e, s);
            }
        }

        ((float4*)p22[buf][wv])[lane] = a22;
        pO[buf][wv][lane] = aO;
        u_cur = u_nxt;
    }

    // tail: finish memo(T-1) + its softmax term
    __syncthreads();
    {
        const int lb = (T - 1) & 1;     // buffer written at t = T-1
        float gO = pO[lb][0][lane] + pO[lb][1][lane]
                 + pO[lb][2][lane] + pO[lb][3][lane];
        float o = bo_r + gO;
        memo = memo * alpha_o + (1.f - alpha_o) * o;
        float e = (lane < D_OUT) ? __expf(memo) : 0.f;
        float s = e;
#pragma unroll
        for (int d = 16; d >= 1; d >>= 1) s += __shfl_xor(s, d, 32);
        if (lane < D_OUT) accv += __fdividef(e, s);
    }

    if (tid < D_OUT) out[bi * D_OUT + tid] = accv;
}

// ---------------------------------------------------------------------------
extern "C" void kernel_launch(void* const* d_in, const int* in_sizes, int n_in,
                              void* d_out, int out_size, void* d_ws, size_t ws_size,
                              hipStream_t stream) {
    const float* x          = (const float*)d_in[0];
    const float* mem1_0     = (const float*)d_in[1];
    const float* mem2_0     = (const float*)d_in[2];
    const float* memo_0     = (const float*)d_in[3];
    const float* Wi1        = (const float*)d_in[4];
    const float* bi1        = (const float*)d_in[5];
    const float* W11        = (const float*)d_in[6];
    const float* b11        = (const float*)d_in[7];
    const float* W12        = (const float*)d_in[8];
    const float* b12        = (const float*)d_in[9];
    const float* W22        = (const float*)d_in[10];
    const float* b22        = (const float*)d_in[11];
    const float* Wo         = (const float*)d_in[12];
    const float* bo         = (const float*)d_in[13];
    const float* tau_adp_h1 = (const float*)d_in[14];
    const float* tau_adp_h2 = (const float*)d_in[15];
    const float* tau_m_h1   = (const float*)d_in[16];
    const float* tau_m_h2   = (const float*)d_in[17];
    const float* tau_m_o    = (const float*)d_in[18];

    float* U    = (float*)d_ws;                         // [32001][256]
    float* Wi1T = U + ((size_t)BATCH * T + 1) * H;      // [705][256]
    float* C1   = Wi1T + N_WI1T;                        // [257][512]
    float* C2   = C1 + N_C;                             // [257][512]

    int prep_total = N_WI1T + 2 * N_C;
    prep_k<<<(prep_total + 255) / 256, 256, 0, stream>>>(
        Wi1, W11, W12, W22, Wo, Wi1T, C1, C2);

    gemm_u_k<<<(BATCH * T) / GR, 256, 0, stream>>>(x, Wi1T, bi1, U);

    recurrent_k<<<BATCH, 256, 0, stream>>>(U, mem1_0, mem2_0, memo_0,
                                           b11, b12, b22, bo,
                                           tau_adp_h1, tau_adp_h2,
                                           tau_m_h1, tau_m_h2, tau_m_o,
                                           C1, C2, (float*)d_out);
}

// Round 6
// 970.613 us; speedup vs baseline: 2.5530x; 2.5530x over previous
//
#include <hip/hip_runtime.h>
#include <math.h>

#define BATCH 128
#define T 250
#define D_IN 700
#define H 256
#define D_OUT 20

// ---------------------------------------------------------------------------
// Workspace layout (fp32):
//   U     [32001][256]  (one pad row for the u-prefetch overrun at t=249)
//   Wi1T  [705][256]    rows 700..704 zero (gemm K-pad + prefetch overrun row)
//   C1    [257][512]    row k, lane l: {W12T[k][4l..4l+3], W11T[k][4l..4l+3]}
//   C2    [257][512]    row k, lane l: {W22T[k][4l..4l+3], Wo[l&31][k], 0,0,0}
//   row 256 of C1/C2 is all-zero (spike-list padding target)
// ---------------------------------------------------------------------------
#define N_WI1T (705 * 256)
#define N_C    (257 * 512)

__global__ void prep_k(const float* __restrict__ Wi1, const float* __restrict__ W11,
                       const float* __restrict__ W12, const float* __restrict__ W22,
                       const float* __restrict__ Wo,
                       float* __restrict__ Wi1T, float* __restrict__ C1,
                       float* __restrict__ C2) {
    int idx = blockIdx.x * 256 + threadIdx.x;
    if (idx < N_WI1T) {
        int k = idx >> 8, h = idx & 255;
        Wi1T[idx] = (k < D_IN) ? Wi1[h * D_IN + k] : 0.f;
        return;
    }
    idx -= N_WI1T;
    if (idx < N_C) {
        int k = idx >> 9, q = idx & 511;
        int l = q >> 3, jj = q & 7;
        float v = 0.f;
        if (k < H) {
            int h = 4 * l + (jj & 3);
            v = (jj < 4) ? W12[h * H + k] : W11[h * H + k];
        }
        C1[idx] = v;
        return;
    }
    idx -= N_C;
    if (idx < N_C) {
        int k = idx >> 9, q = idx & 511;
        int l = q >> 3, jj = q & 7;
        float v = 0.f;
        if (k < H) {
            if (jj < 4) v = W22[(4 * l + jj) * H + k];
            else if (jj == 4 && (l & 31) < D_OUT) v = Wo[(l & 31) * H + k];
        }
        C2[idx] = v;
    }
}

// ---------------------------------------------------------------------------
// U = x @ Wi1^T + bi1.  64-row tile, 500 blocks (~2/CU), thread = 8 rows x 8 cols.
// (unchanged from R4 — proven)
// ---------------------------------------------------------------------------
#define GR 64
#define GK 64
__global__ __launch_bounds__(256) void gemm_u_k(const float* __restrict__ x,
                                                const float* __restrict__ Wi1T,
                                                const float* __restrict__ bi1,
                                                float* __restrict__ U) {
    __shared__ float xs[GK][GR + 4];
    int tid = threadIdx.x;
    int c0 = (tid & 31) * 8;
    int r0 = (tid >> 5) * 8;
    int m0 = blockIdx.x * GR;

    float4 a0[8], a1[8];
#pragma unroll
    for (int r = 0; r < 8; ++r) {
        a0[r] = make_float4(0.f, 0.f, 0.f, 0.f);
        a1[r] = make_float4(0.f, 0.f, 0.f, 0.f);
    }

    for (int k0 = 0; k0 < 704; k0 += GK) {
        __syncthreads();
#pragma unroll
        for (int i = 0; i < 4; ++i) {
            int f = tid + (i << 8);
            int r = f >> 4, c4 = (f & 15) << 2;
            int k = k0 + c4;
            float4 v = make_float4(0.f, 0.f, 0.f, 0.f);
            if (k < D_IN) v = *(const float4*)(x + (size_t)(m0 + r) * D_IN + k);
            xs[c4 + 0][r] = v.x; xs[c4 + 1][r] = v.y;
            xs[c4 + 2][r] = v.z; xs[c4 + 3][r] = v.w;
        }
        __syncthreads();

        const float* wp = Wi1T + (size_t)k0 * H + c0;
        float4 w0 = *(const float4*)(wp);
        float4 w1 = *(const float4*)(wp + 4);
        for (int k = 0; k < GK; ++k) {
            const float* wn = Wi1T + (size_t)(k0 + k + 1) * H + c0;
            float4 nw0 = *(const float4*)(wn);
            float4 nw1 = *(const float4*)(wn + 4);
            float4 xa = *(const float4*)(&xs[k][r0]);
            float4 xb = *(const float4*)(&xs[k][r0 + 4]);
            float xv[8] = {xa.x, xa.y, xa.z, xa.w, xb.x, xb.y, xb.z, xb.w};
#pragma unroll
            for (int r = 0; r < 8; ++r) {
                float xr = xv[r];
                a0[r].x += xr * w0.x; a0[r].y += xr * w0.y;
                a0[r].z += xr * w0.z; a0[r].w += xr * w0.w;
                a1[r].x += xr * w1.x; a1[r].y += xr * w1.y;
                a1[r].z += xr * w1.z; a1[r].w += xr * w1.w;
            }
            w0 = nw0; w1 = nw1;
        }
    }

    float4 bb0 = *(const float4*)(bi1 + c0);
    float4 bb1 = *(const float4*)(bi1 + c0 + 4);
#pragma unroll
    for (int r = 0; r < 8; ++r) {
        float* up = U + (size_t)(m0 + r0 + r) * H + c0;
        float4 o0, o1;
        o0.x = a0[r].x + bb0.x; o0.y = a0[r].y + bb0.y;
        o0.z = a0[r].z + bb0.z; o0.w = a0[r].w + bb0.w;
        o1.x = a1[r].x + bb1.x; o1.y = a1[r].y + bb1.y;
        o1.z = a1[r].z + bb1.z; o1.w = a1[r].w + bb1.w;
        *(float4*)(up) = o0;
        *(float4*)(up + 4) = o1;
    }
}

// ---------------------------------------------------------------------------
// Recurrent: one WAVE per batch element (no barriers). Depth-2 ring gathers
// with STATICALLY-indexed double buffers (no scratch spill). u prefetched one
// step ahead; output/softmax deferred one step (off critical path).
// ---------------------------------------------------------------------------

__device__ __forceinline__ int build_list(unsigned int* list, int lane,
                                          float sx, float sy, float sz, float sw) {
    unsigned long long m0 = __ballot(sx > 0.f);
    unsigned long long m1 = __ballot(sy > 0.f);
    unsigned long long m2 = __ballot(sz > 0.f);
    unsigned long long m3 = __ballot(sw > 0.f);
    unsigned long long below = (1ull << lane) - 1ull;
    int c0 = __popcll(m0), c1 = __popcll(m1), c2 = __popcll(m2), c3 = __popcll(m3);
    int n = c0 + c1 + c2 + c3;
    if ((m0 >> lane) & 1) list[__popcll(m0 & below)] = lane * 4;
    if ((m1 >> lane) & 1) list[c0 + __popcll(m1 & below)] = lane * 4 + 1;
    if ((m2 >> lane) & 1) list[c0 + c1 + __popcll(m2 & below)] = lane * 4 + 2;
    if ((m3 >> lane) & 1) list[c0 + c1 + c2 + __popcll(m3 & below)] = lane * 4 + 3;
    list[n + lane] = 256;                   // 64 pad entries -> zero weight row
    __builtin_amdgcn_wave_barrier();
    return n;
}

// Depth-2 ring gather over C1 rows: A += C[row][l8..l8+3], B += C[row][l8+4..l8+7].
// nb = number of 8-row batches, even, >= 2. All register arrays statically indexed.
__device__ __forceinline__ void gather_c1(const unsigned int* lst, int nb,
                                          const float* __restrict__ C,
                                          unsigned l8, float4& A, float4& B) {
    float4 a0[8], b0[8], a1[8], b1[8];
    {
        uint4 ia = *(const uint4*)(lst);
        uint4 ib = *(const uint4*)(lst + 4);
        unsigned I[8] = {ia.x, ia.y, ia.z, ia.w, ib.x, ib.y, ib.z, ib.w};
#pragma unroll
        for (int j = 0; j < 8; ++j) {
            const float* p = C + (I[j] << 9) + l8;
            a0[j] = *(const float4*)(p);
            b0[j] = *(const float4*)(p + 4);
        }
    }
    {
        uint4 ia = *(const uint4*)(lst + 8);
        uint4 ib = *(const uint4*)(lst + 12);
        unsigned I[8] = {ia.x, ia.y, ia.z, ia.w, ib.x, ib.y, ib.z, ib.w};
#pragma unroll
        for (int j = 0; j < 8; ++j) {
            const float* p = C + (I[j] << 9) + l8;
            a1[j] = *(const float4*)(p);
            b1[j] = *(const float4*)(p + 4);
        }
    }
    for (int b = 2; b < nb; b += 2) {
        {   // consume slot0 (batch b-2), refill slot0 with batch b
            uint4 ia = *(const uint4*)(lst + 8 * b);
            uint4 ib = *(const uint4*)(lst + 8 * b + 4);
            unsigned N[8] = {ia.x, ia.y, ia.z, ia.w, ib.x, ib.y, ib.z, ib.w};
#pragma unroll
            for (int j = 0; j < 8; ++j) {
                A.x += a0[j].x; A.y += a0[j].y; A.z += a0[j].z; A.w += a0[j].w;
                B.x += b0[j].x; B.y += b0[j].y; B.z += b0[j].z; B.w += b0[j].w;
                const float* p = C + (N[j] << 9) + l8;
                a0[j] = *(const float4*)(p);
                b0[j] = *(const float4*)(p + 4);
            }
        }
        {   // consume slot1 (batch b-1), refill slot1 with batch b+1
            uint4 ia = *(const uint4*)(lst + 8 * (b + 1));
            uint4 ib = *(const uint4*)(lst + 8 * (b + 1) + 4);
            unsigned M[8] = {ia.x, ia.y, ia.z, ia.w, ib.x, ib.y, ib.z, ib.w};
#pragma unroll
            for (int j = 0; j < 8; ++j) {
                A.x += a1[j].x; A.y += a1[j].y; A.z += a1[j].z; A.w += a1[j].w;
                B.x += b1[j].x; B.y += b1[j].y; B.z += b1[j].z; B.w += b1[j].w;
                const float* p = C + (M[j] << 9) + l8;
                a1[j] = *(const float4*)(p);
                b1[j] = *(const float4*)(p + 4);
            }
        }
    }
#pragma unroll
    for (int j = 0; j < 8; ++j) {
        A.x += a0[j].x; A.y += a0[j].y; A.z += a0[j].z; A.w += a0[j].w;
        B.x += b0[j].x; B.y += b0[j].y; B.z += b0[j].z; B.w += b0[j].w;
    }
#pragma unroll
    for (int j = 0; j < 8; ++j) {
        A.x += a1[j].x; A.y += a1[j].y; A.z += a1[j].z; A.w += a1[j].w;
        B.x += b1[j].x; B.y += b1[j].y; B.z += b1[j].z; B.w += b1[j].w;
    }
}

// Same, for C2 rows: A += C[row][l8..l8+3] (W22), O += C[row][l8+4] (Wo col).
__device__ __forceinline__ void gather_c2(const unsigned int* lst, int nb,
                                          const float* __restrict__ C,
                                          unsigned l8, float4& A, float& O) {
    float4 a0[8], a1[8]; float o0[8], o1[8];
    {
        uint4 ia = *(const uint4*)(lst);
        uint4 ib = *(const uint4*)(lst + 4);
        unsigned I[8] = {ia.x, ia.y, ia.z, ia.w, ib.x, ib.y, ib.z, ib.w};
#pragma unroll
        for (int j = 0; j < 8; ++j) {
            const float* p = C + (I[j] << 9) + l8;
            a0[j] = *(const float4*)(p);
            o0[j] = p[4];
        }
    }
    {
        uint4 ia = *(const uint4*)(lst + 8);
        uint4 ib = *(const uint4*)(lst + 12);
        unsigned I[8] = {ia.x, ia.y, ia.z, ia.w, ib.x, ib.y, ib.z, ib.w};
#pragma unroll
        for (int j = 0; j < 8; ++j) {
            const float* p = C + (I[j] << 9) + l8;
            a1[j] = *(const float4*)(p);
            o1[j] = p[4];
        }
    }
    for (int b = 2; b < nb; b += 2) {
        {
            uint4 ia = *(const uint4*)(lst + 8 * b);
            uint4 ib = *(const uint4*)(lst + 8 * b + 4);
            unsigned N[8] = {ia.x, ia.y, ia.z, ia.w, ib.x, ib.y, ib.z, ib.w};
#pragma unroll
            for (int j = 0; j < 8; ++j) {
                A.x += a0[j].x; A.y += a0[j].y; A.z += a0[j].z; A.w += a0[j].w;
                O += o0[j];
                const float* p = C + (N[j] << 9) + l8;
                a0[j] = *(const float4*)(p);
                o0[j] = p[4];
            }
        }
        {
            uint4 ia = *(const uint4*)(lst + 8 * (b + 1));
            uint4 ib = *(const uint4*)(lst + 8 * (b + 1) + 4);
            unsigned M[8] = {ia.x, ia.y, ia.z, ia.w, ib.x, ib.y, ib.z, ib.w};
#pragma unroll
            for (int j = 0; j < 8; ++j) {
                A.x += a1[j].x; A.y += a1[j].y; A.z += a1[j].z; A.w += a1[j].w;
                O += o1[j];
                const float* p = C + (M[j] << 9) + l8;
                a1[j] = *(const float4*)(p);
                o1[j] = p[4];
            }
        }
    }
#pragma unroll
    for (int j = 0; j < 8; ++j) {
        A.x += a0[j].x; A.y += a0[j].y; A.z += a0[j].z; A.w += a0[j].w;
        O += o0[j];
    }
#pragma unroll
    for (int j = 0; j < 8; ++j) {
        A.x += a1[j].x; A.y += a1[j].y; A.z += a1[j].z; A.w += a1[j].w;
        O += o1[j];
    }
}

__global__ __launch_bounds__(64, 1) void recurrent_k(
    const float* __restrict__ U,
    const float* __restrict__ mem1_0, const float* __restrict__ mem2_0,
    const float* __restrict__ memo_0,
    const float* __restrict__ b11v, const float* __restrict__ b12v,
    const float* __restrict__ b22v, const float* __restrict__ bov,
    const float* __restrict__ tau_adp_h1, const float* __restrict__ tau_adp_h2,
    const float* __restrict__ tau_m_h1, const float* __restrict__ tau_m_h2,
    const float* __restrict__ tau_m_o,
    const float* __restrict__ C1, const float* __restrict__ C2,
    float* __restrict__ out)
{
    const int lane = threadIdx.x;
    const int bi = blockIdx.x;
    const unsigned laneOff = lane * 4;
    const unsigned l8 = lane * 8;

    __shared__ __align__(16) unsigned int list1[320], list2[320];

    float4 mem1 = *(const float4*)(mem1_0 + bi * H + laneOff);
    float4 mem2 = *(const float4*)(mem2_0 + bi * H + laneOff);
    float4 b1 = make_float4(0.01f, 0.01f, 0.01f, 0.01f);
    float4 b2 = make_float4(0.01f, 0.01f, 0.01f, 0.01f);
    float4 spk1 = make_float4(0.f, 0.f, 0.f, 0.f);
    float4 spk2 = make_float4(0.f, 0.f, 0.f, 0.f);

    float4 tm1 = *(const float4*)(tau_m_h1 + laneOff);
    float4 ta1 = *(const float4*)(tau_adp_h1 + laneOff);
    float4 tm2 = *(const float4*)(tau_m_h2 + laneOff);
    float4 ta2 = *(const float4*)(tau_adp_h2 + laneOff);
    float4 al1, ro1, al2, ro2;
    al1.x = expf(-1.f / tm1.x); al1.y = expf(-1.f / tm1.y);
    al1.z = expf(-1.f / tm1.z); al1.w = expf(-1.f / tm1.w);
    ro1.x = expf(-1.f / ta1.x); ro1.y = expf(-1.f / ta1.y);
    ro1.z = expf(-1.f / ta1.z); ro1.w = expf(-1.f / ta1.w);
    al2.x = expf(-1.f / tm2.x); al2.y = expf(-1.f / tm2.y);
    al2.z = expf(-1.f / tm2.z); al2.w = expf(-1.f / tm2.w);
    ro2.x = expf(-1.f / ta2.x); ro2.y = expf(-1.f / ta2.y);
    ro2.z = expf(-1.f / ta2.z); ro2.w = expf(-1.f / ta2.w);
    float4 oma1, omr1, oma2, omr2;
    oma1.x = 1.f - al1.x; oma1.y = 1.f - al1.y; oma1.z = 1.f - al1.z; oma1.w = 1.f - al1.w;
    omr1.x = 1.f - ro1.x; omr1.y = 1.f - ro1.y; omr1.z = 1.f - ro1.z; omr1.w = 1.f - ro1.w;
    oma2.x = 1.f - al2.x; oma2.y = 1.f - al2.y; oma2.z = 1.f - al2.z; oma2.w = 1.f - al2.w;
    omr2.x = 1.f - ro2.x; omr2.y = 1.f - ro2.y; omr2.z = 1.f - ro2.z; omr2.w = 1.f - ro2.w;

    float4 b11r = *(const float4*)(b11v + laneOff);
    float4 b12r = *(const float4*)(b12v + laneOff);
    float4 b22r = *(const float4*)(b22v + laneOff);
    float4 bsum2;
    bsum2.x = b12r.x + b22r.x; bsum2.y = b12r.y + b22r.y;
    bsum2.z = b12r.z + b22r.z; bsum2.w = b12r.w + b22r.w;

    float memo = 0.f, alpha_o = 0.f, bo_r = 0.f, accv = 0.f;
    if (lane < D_OUT) {
        memo = memo_0[bi * D_OUT + lane];
        alpha_o = expf(-1.f / tau_m_o[lane]);
        bo_r = bov[lane];
    }

    // carried across steps
    float4 g11c = make_float4(0.f, 0.f, 0.f, 0.f);   // W11 @ sp1(t-1)
    float4 g22c = make_float4(0.f, 0.f, 0.f, 0.f);   // W22 @ sp2(t-1)
    float aOc = 0.f;                                  // Wo  @ sp2(t-1)

    const float* Up = U + (size_t)bi * T * H + laneOff;
    float4 u_cur = *(const float4*)(Up);

    for (int t = 0; t < T; ++t) {
        float4 u_nxt = *(const float4*)(Up + H);   // prefetch (pad row at end)
        Up += H;

        // ---- deferred output for step t-1 (off critical path)
        if (t >= 1) {
            float o = bo_r + aOc;
            memo = memo * alpha_o + (1.f - alpha_o) * o;
            if (t >= 12) {                          // (t-1) > 10
                float e = (lane < D_OUT) ? __expf(memo) : 0.f;
                float s = e;
#pragma unroll
                for (int d = 16; d >= 1; d >>= 1) s += __shfl_xor(s, d, 32);
                if (lane < D_OUT) accv += __fdividef(e, s);
            }
        }

        // ---- layer 1 update (carried g11c, prefetched u_cur)
        float4 h1;
        h1.x = u_cur.x + b11r.x + g11c.x; h1.y = u_cur.y + b11r.y + g11c.y;
        h1.z = u_cur.z + b11r.z + g11c.z; h1.w = u_cur.w + b11r.w + g11c.w;
        b1.x = ro1.x * b1.x + omr1.x * spk1.x; b1.y = ro1.y * b1.y + omr1.y * spk1.y;
        b1.z = ro1.z * b1.z + omr1.z * spk1.z; b1.w = ro1.w * b1.w + omr1.w * spk1.w;
        float B1x = 0.01f + 1.8f * b1.x, B1y = 0.01f + 1.8f * b1.y;
        float B1z = 0.01f + 1.8f * b1.z, B1w = 0.01f + 1.8f * b1.w;
        mem1.x = mem1.x * al1.x + oma1.x * h1.x - B1x * spk1.x;
        mem1.y = mem1.y * al1.y + oma1.y * h1.y - B1y * spk1.y;
        mem1.z = mem1.z * al1.z + oma1.z * h1.z - B1z * spk1.z;
        mem1.w = mem1.w * al1.w + oma1.w * h1.w - B1w * spk1.w;
        spk1.x = (mem1.x - B1x > 0.f) ? 1.f : 0.f;
        spk1.y = (mem1.y - B1y > 0.f) ? 1.f : 0.f;
        spk1.z = (mem1.z - B1z > 0.f) ? 1.f : 0.f;
        spk1.w = (mem1.w - B1w > 0.f) ? 1.f : 0.f;

        int n1 = build_list(list1, lane, spk1.x, spk1.y, spk1.z, spk1.w);
        int n16 = (n1 + 15) & ~15; if (n16 < 16) n16 = 16;
        int nb1 = n16 >> 3;                         // even, >= 2

        float4 g12 = make_float4(0.f, 0.f, 0.f, 0.f);
        float4 g11n = make_float4(0.f, 0.f, 0.f, 0.f);
        gather_c1(list1, nb1, C1, l8, g12, g11n);

        // ---- layer 2 update (fresh g12, carried g22c)
        float4 h2;
        h2.x = bsum2.x + g22c.x + g12.x; h2.y = bsum2.y + g22c.y + g12.y;
        h2.z = bsum2.z + g22c.z + g12.z; h2.w = bsum2.w + g22c.w + g12.w;
        b2.x = ro2.x * b2.x + omr2.x * spk2.x; b2.y = ro2.y * b2.y + omr2.y * spk2.y;
        b2.z = ro2.z * b2.z + omr2.z * spk2.z; b2.w = ro2.w * b2.w + omr2.w * spk2.w;
        float B2x = 0.01f + 1.8f * b2.x, B2y = 0.01f + 1.8f * b2.y;
        float B2z = 0.01f + 1.8f * b2.z, B2w = 0.01f + 1.8f * b2.w;
        mem2.x = mem2.x * al2.x + oma2.x * h2.x - B2x * spk2.x;
        mem2.y = mem2.y * al2.y + oma2.y * h2.y - B2y * spk2.y;
        mem2.z = mem2.z * al2.z + oma2.z * h2.z - B2z * spk2.z;
        mem2.w = mem2.w * al2.w + oma2.w * h2.w - B2w * spk2.w;
        spk2.x = (mem2.x - B2x > 0.f) ? 1.f : 0.f;
        spk2.y = (mem2.y - B2y > 0.f) ? 1.f : 0.f;
        spk2.z = (mem2.z - B2z > 0.f) ? 1.f : 0.f;
        spk2.w = (mem2.w - B2w > 0.f) ? 1.f : 0.f;

        int n2 = build_list(list2, lane, spk2.x, spk2.y, spk2.z, spk2.w);
        int m16 = (n2 + 15) & ~15; if (m16 < 16) m16 = 16;
        int nb2 = m16 >> 3;

        float4 g22n = make_float4(0.f, 0.f, 0.f, 0.f);
        float aOn = 0.f;
        gather_c2(list2, nb2, C2, l8, g22n, aOn);

        g11c = g11n;
        g22c = g22n;
        aOc = aOn;
        u_cur = u_nxt;
    }

    // tail: finish memo(T-1) + its softmax term
    {
        float o = bo_r + aOc;
        memo = memo * alpha_o + (1.f - alpha_o) * o;
        float e = (lane < D_OUT) ? __expf(memo) : 0.f;
        float s = e;
#pragma unroll
        for (int d = 16; d >= 1; d >>= 1) s += __shfl_xor(s, d, 32);
        if (lane < D_OUT) accv += __fdividef(e, s);
    }

    if (lane < D_OUT) out[bi * D_OUT + lane] = accv;
}

// ---------------------------------------------------------------------------
extern "C" void kernel_launch(void* const* d_in, const int* in_sizes, int n_in,
                              void* d_out, int out_size, void* d_ws, size_t ws_size,
                              hipStream_t stream) {
    const float* x          = (const float*)d_in[0];
    const float* mem1_0     = (const float*)d_in[1];
    const float* mem2_0     = (const float*)d_in[2];
    const float* memo_0     = (const float*)d_in[3];
    const float* Wi1        = (const float*)d_in[4];
    const float* bi1        = (const float*)d_in[5];
    const float* W11        = (const float*)d_in[6];
    const float* b11        = (const float*)d_in[7];
    const float* W12        = (const float*)d_in[8];
    const float* b12        = (const float*)d_in[9];
    const float* W22        = (const float*)d_in[10];
    const float* b22        = (const float*)d_in[11];
    const float* Wo         = (const float*)d_in[12];
    const float* bo         = (const float*)d_in[13];
    const float* tau_adp_h1 = (const float*)d_in[14];
    const float* tau_adp_h2 = (const float*)d_in[15];
    const float* tau_m_h1   = (const float*)d_in[16];
    const float* tau_m_h2   = (const float*)d_in[17];
    const float* tau_m_o    = (const float*)d_in[18];

    float* U    = (float*)d_ws;                         // [32001][256]
    float* Wi1T = U + ((size_t)BATCH * T + 1) * H;      // [705][256]
    float* C1   = Wi1T + N_WI1T;                        // [257][512]
    float* C2   = C1 + N_C;                             // [257][512]

    int prep_total = N_WI1T + 2 * N_C;
    prep_k<<<(prep_total + 255) / 256, 256, 0, stream>>>(
        Wi1, W11, W12, W22, Wo, Wi1T, C1, C2);

    gemm_u_k<<<(BATCH * T) / GR, 256, 0, stream>>>(x, Wi1T, bi1, U);

    recurrent_k<<<BATCH, 64, 0, stream>>>(U, mem1_0, mem2_0, memo_0,
                                          b11, b12, b22, bo,
                                          tau_adp_h1, tau_adp_h2,
                                          tau_m_h1, tau_m_h2, tau_m_o,
                                          C1, C2, (float*)d_out);
}

// Round 7
// 876.593 us; speedup vs baseline: 2.8268x; 1.1073x over previous
//
#include <hip/hip_runtime.h>
#include <math.h>

#define BATCH 128
#define T 250
#define D_IN 700
#define H 256
#define D_OUT 20

typedef float v2f __attribute__((ext_vector_type(2)));

// ---------------------------------------------------------------------------
// Workspace layout (fp32):
//   U     [32001][256]  (one pad row for the u-prefetch overrun at t=249)
//   Wi1T  [705][256]    rows 700..704 zero (gemm K-pad + prefetch overrun row)
//   C1    [257][512]    row k, lane l: {W12T[k][4l..4l+3], W11T[k][4l..4l+3]}
//   C2    [257][512]    row k, lane l: {W22T[k][4l..4l+3], Wo[l&31][k], 0,0,0}
//   row 256 of C1/C2 is all-zero (spike-list padding target)
// ---------------------------------------------------------------------------
#define N_WI1T (705 * 256)
#define N_C    (257 * 512)

__global__ void prep_k(const float* __restrict__ Wi1, const float* __restrict__ W11,
                       const float* __restrict__ W12, const float* __restrict__ W22,
                       const float* __restrict__ Wo,
                       float* __restrict__ Wi1T, float* __restrict__ C1,
                       float* __restrict__ C2) {
    int idx = blockIdx.x * 256 + threadIdx.x;
    if (idx < N_WI1T) {
        int k = idx >> 8, h = idx & 255;
        Wi1T[idx] = (k < D_IN) ? Wi1[h * D_IN + k] : 0.f;
        return;
    }
    idx -= N_WI1T;
    if (idx < N_C) {
        int k = idx >> 9, q = idx & 511;
        int l = q >> 3, jj = q & 7;
        float v = 0.f;
        if (k < H) {
            int h = 4 * l + (jj & 3);
            v = (jj < 4) ? W12[h * H + k] : W11[h * H + k];
        }
        C1[idx] = v;
        return;
    }
    idx -= N_C;
    if (idx < N_C) {
        int k = idx >> 9, q = idx & 511;
        int l = q >> 3, jj = q & 7;
        float v = 0.f;
        if (k < H) {
            if (jj < 4) v = W22[(4 * l + jj) * H + k];
            else if (jj == 4 && (l & 31) < D_OUT) v = Wo[(l & 31) * H + k];
        }
        C2[idx] = v;
    }
}

// ---------------------------------------------------------------------------
// U = x @ Wi1^T + bi1.  64-row tile, 500 blocks (~2/CU), thread = 8 rows x 8 cols.
// Inner products via float2 vectors -> v_pk_fma_f32 (dual-issue fp32).
// ---------------------------------------------------------------------------
#define GR 64
#define GK 64
__global__ __launch_bounds__(256) void gemm_u_k(const float* __restrict__ x,
                                                const float* __restrict__ Wi1T,
                                                const float* __restrict__ bi1,
                                                float* __restrict__ U) {
    __shared__ float xs[GK][GR + 4];
    int tid = threadIdx.x;
    int c0 = (tid & 31) * 8;
    int r0 = (tid >> 5) * 8;
    int m0 = blockIdx.x * GR;

    v2f acc[8][4];
#pragma unroll
    for (int r = 0; r < 8; ++r)
#pragma unroll
        for (int c = 0; c < 4; ++c) acc[r][c] = (v2f)(0.f);

    for (int k0 = 0; k0 < 704; k0 += GK) {
        __syncthreads();
#pragma unroll
        for (int i = 0; i < 4; ++i) {
            int f = tid + (i << 8);
            int r = f >> 4, c4 = (f & 15) << 2;
            int k = k0 + c4;
            float4 v = make_float4(0.f, 0.f, 0.f, 0.f);
            if (k < D_IN) v = *(const float4*)(x + (size_t)(m0 + r) * D_IN + k);
            xs[c4 + 0][r] = v.x; xs[c4 + 1][r] = v.y;
            xs[c4 + 2][r] = v.z; xs[c4 + 3][r] = v.w;
        }
        __syncthreads();

        const float* wp = Wi1T + (size_t)k0 * H + c0;
        float4 w0 = *(const float4*)(wp);
        float4 w1 = *(const float4*)(wp + 4);
        for (int k = 0; k < GK; ++k) {
            const float* wn = Wi1T + (size_t)(k0 + k + 1) * H + c0;
            float4 nw0 = *(const float4*)(wn);
            float4 nw1 = *(const float4*)(wn + 4);
            float4 xa = *(const float4*)(&xs[k][r0]);
            float4 xb = *(const float4*)(&xs[k][r0 + 4]);
            float xv[8] = {xa.x, xa.y, xa.z, xa.w, xb.x, xb.y, xb.z, xb.w};
            v2f wv0 = {w0.x, w0.y}, wv1 = {w0.z, w0.w};
            v2f wv2 = {w1.x, w1.y}, wv3 = {w1.z, w1.w};
#pragma unroll
            for (int r = 0; r < 8; ++r) {
                v2f xx = {xv[r], xv[r]};
                acc[r][0] += xx * wv0;
                acc[r][1] += xx * wv1;
                acc[r][2] += xx * wv2;
                acc[r][3] += xx * wv3;
            }
            w0 = nw0; w1 = nw1;
        }
    }

    float4 bb0 = *(const float4*)(bi1 + c0);
    float4 bb1 = *(const float4*)(bi1 + c0 + 4);
#pragma unroll
    for (int r = 0; r < 8; ++r) {
        float* up = U + (size_t)(m0 + r0 + r) * H + c0;
        float4 o0, o1;
        o0.x = acc[r][0].x + bb0.x; o0.y = acc[r][0].y + bb0.y;
        o0.z = acc[r][1].x + bb0.z; o0.w = acc[r][1].y + bb0.w;
        o1.x = acc[r][2].x + bb1.x; o1.y = acc[r][2].y + bb1.y;
        o1.z = acc[r][3].x + bb1.z; o1.w = acc[r][3].y + bb1.w;
        *(float4*)(up) = o0;
        *(float4*)(up + 4) = o1;
    }
}

// ---------------------------------------------------------------------------
// Recurrent: one WAVE per batch element (no barriers). Depth-2 ring gathers
// with statically-indexed buffers AND index-batch prefetch (lgkm hidden).
// Consumes via float2 -> v_pk_add_f32. u prefetched; softmax deferred a step.
// ---------------------------------------------------------------------------

__device__ __forceinline__ int build_list(unsigned int* list, int lane,
                                          float sx, float sy, float sz, float sw) {
    unsigned long long m0 = __ballot(sx > 0.f);
    unsigned long long m1 = __ballot(sy > 0.f);
    unsigned long long m2 = __ballot(sz > 0.f);
    unsigned long long m3 = __ballot(sw > 0.f);
    unsigned long long below = (1ull << lane) - 1ull;
    int c0 = __popcll(m0), c1 = __popcll(m1), c2 = __popcll(m2), c3 = __popcll(m3);
    int n = c0 + c1 + c2 + c3;
    if ((m0 >> lane) & 1) list[__popcll(m0 & below)] = lane * 4;
    if ((m1 >> lane) & 1) list[c0 + __popcll(m1 & below)] = lane * 4 + 1;
    if ((m2 >> lane) & 1) list[c0 + c1 + __popcll(m2 & below)] = lane * 4 + 2;
    if ((m3 >> lane) & 1) list[c0 + c1 + c2 + __popcll(m3 & below)] = lane * 4 + 3;
    list[n + lane] = 256;                   // 64 pad entries -> zero weight row
    __builtin_amdgcn_wave_barrier();
    return n;
}

// Depth-2 ring gather over C1 rows with index prefetch.
// Accumulates A (+l8..l8+3) into A0/A1 pairs and B (+l8+4..l8+7) into B0/B1.
// nb even, >= 2. LDS reads reach lst[8*nb+15] max -> list sized 384.
__device__ __forceinline__ void gather_c1(const unsigned int* lst, int nb,
                                          const float* __restrict__ C,
                                          unsigned l8,
                                          v2f& A0, v2f& A1, v2f& B0, v2f& B1) {
    float4 wa0[8], wb0[8], wa1[8], wb1[8];
    {
        uint4 ia = *(const uint4*)(lst);
        uint4 ib = *(const uint4*)(lst + 4);
        unsigned I[8] = {ia.x, ia.y, ia.z, ia.w, ib.x, ib.y, ib.z, ib.w};
#pragma unroll
        for (int j = 0; j < 8; ++j) {
            const float* p = C + (I[j] << 9) + l8;
            wa0[j] = *(const float4*)(p);
            wb0[j] = *(const float4*)(p + 4);
        }
    }
    {
        uint4 ia = *(const uint4*)(lst + 8);
        uint4 ib = *(const uint4*)(lst + 12);
        unsigned I[8] = {ia.x, ia.y, ia.z, ia.w, ib.x, ib.y, ib.z, ib.w};
#pragma unroll
        for (int j = 0; j < 8; ++j) {
            const float* p = C + (I[j] << 9) + l8;
            wa1[j] = *(const float4*)(p);
            wb1[j] = *(const float4*)(p + 4);
        }
    }
    // prefetched index batches (b+2 pair); reads may touch pad/garbage区 -> never
    // used as addresses unless batch < nb (list allocated to 384 entries).
    uint4 p0a = *(const uint4*)(lst + 16);
    uint4 p0b = *(const uint4*)(lst + 20);
    uint4 p1a = *(const uint4*)(lst + 24);
    uint4 p1b = *(const uint4*)(lst + 28);

    for (int b = 2; b < nb; b += 2) {
        {
            unsigned N[8] = {p0a.x, p0a.y, p0a.z, p0a.w, p0b.x, p0b.y, p0b.z, p0b.w};
#pragma unroll
            for (int j = 0; j < 8; ++j) {
                const v2f* w = (const v2f*)&wa0[j];
                A0 += w[0]; A1 += w[1];
                const v2f* v = (const v2f*)&wb0[j];
                B0 += v[0]; B1 += v[1];
                const float* p = C + (N[j] << 9) + l8;
                wa0[j] = *(const float4*)(p);
                wb0[j] = *(const float4*)(p + 4);
            }
            p0a = *(const uint4*)(lst + 8 * b + 16);
            p0b = *(const uint4*)(lst + 8 * b + 20);
        }
        {
            unsigned M[8] = {p1a.x, p1a.y, p1a.z, p1a.w, p1b.x, p1b.y, p1b.z, p1b.w};
#pragma unroll
            for (int j = 0; j < 8; ++j) {
                const v2f* w = (const v2f*)&wa1[j];
                A0 += w[0]; A1 += w[1];
                const v2f* v = (const v2f*)&wb1[j];
                B0 += v[0]; B1 += v[1];
                const float* p = C + (M[j] << 9) + l8;
                wa1[j] = *(const float4*)(p);
                wb1[j] = *(const float4*)(p + 4);
            }
            p1a = *(const uint4*)(lst + 8 * b + 24);
            p1b = *(const uint4*)(lst + 8 * b + 28);
        }
    }
#pragma unroll
    for (int j = 0; j < 8; ++j) {
        const v2f* w = (const v2f*)&wa0[j];
        A0 += w[0]; A1 += w[1];
        const v2f* v = (const v2f*)&wb0[j];
        B0 += v[0]; B1 += v[1];
    }
#pragma unroll
    for (int j = 0; j < 8; ++j) {
        const v2f* w = (const v2f*)&wa1[j];
        A0 += w[0]; A1 += w[1];
        const v2f* v = (const v2f*)&wb1[j];
        B0 += v[0]; B1 += v[1];
    }
}

// Same for C2 rows: A (+l8..l8+3, W22) into A0/A1, scalar Wo col (+l8+4) into O.
__device__ __forceinline__ void gather_c2(const unsigned int* lst, int nb,
                                          const float* __restrict__ C,
                                          unsigned l8,
                                          v2f& A0, v2f& A1, float& O) {
    float4 wa0[8], wa1[8]; float o0[8], o1[8];
    {
        uint4 ia = *(const uint4*)(lst);
        uint4 ib = *(const uint4*)(lst + 4);
        unsigned I[8] = {ia.x, ia.y, ia.z, ia.w, ib.x, ib.y, ib.z, ib.w};
#pragma unroll
        for (int j = 0; j < 8; ++j) {
            const float* p = C + (I[j] << 9) + l8;
            wa0[j] = *(const float4*)(p);
            o0[j] = p[4];
        }
    }
    {
        uint4 ia = *(const uint4*)(lst + 8);
        uint4 ib = *(const uint4*)(lst + 12);
        unsigned I[8] = {ia.x, ia.y, ia.z, ia.w, ib.x, ib.y, ib.z, ib.w};
#pragma unroll
        for (int j = 0; j < 8; ++j) {
            const float* p = C + (I[j] << 9) + l8;
            wa1[j] = *(const float4*)(p);
            o1[j] = p[4];
        }
    }
    uint4 p0a = *(const uint4*)(lst + 16);
    uint4 p0b = *(const uint4*)(lst + 20);
    uint4 p1a = *(const uint4*)(lst + 24);
    uint4 p1b = *(const uint4*)(lst + 28);

    for (int b = 2; b < nb; b += 2) {
        {
            unsigned N[8] = {p0a.x, p0a.y, p0a.z, p0a.w, p0b.x, p0b.y, p0b.z, p0b.w};
#pragma unroll
            for (int j = 0; j < 8; ++j) {
                const v2f* w = (const v2f*)&wa0[j];
                A0 += w[0]; A1 += w[1];
                O += o0[j];
                const float* p = C + (N[j] << 9) + l8;
                wa0[j] = *(const float4*)(p);
                o0[j] = p[4];
            }
            p0a = *(const uint4*)(lst + 8 * b + 16);
            p0b = *(const uint4*)(lst + 8 * b + 20);
        }
        {
            unsigned M[8] = {p1a.x, p1a.y, p1a.z, p1a.w, p1b.x, p1b.y, p1b.z, p1b.w};
#pragma unroll
            for (int j = 0; j < 8; ++j) {
                const v2f* w = (const v2f*)&wa1[j];
                A0 += w[0]; A1 += w[1];
                O += o1[j];
                const float* p = C + (M[j] << 9) + l8;
                wa1[j] = *(const float4*)(p);
                o1[j] = p[4];
            }
            p1a = *(const uint4*)(lst + 8 * b + 24);
            p1b = *(const uint4*)(lst + 8 * b + 28);
        }
    }
#pragma unroll
    for (int j = 0; j < 8; ++j) {
        const v2f* w = (const v2f*)&wa0[j];
        A0 += w[0]; A1 += w[1];
        O += o0[j];
    }
#pragma unroll
    for (int j = 0; j < 8; ++j) {
        const v2f* w = (const v2f*)&wa1[j];
        A0 += w[0]; A1 += w[1];
        O += o1[j];
    }
}

__global__ __launch_bounds__(64, 1) void recurrent_k(
    const float* __restrict__ U,
    const float* __restrict__ mem1_0, const float* __restrict__ mem2_0,
    const float* __restrict__ memo_0,
    const float* __restrict__ b11v, const float* __restrict__ b12v,
    const float* __restrict__ b22v, const float* __restrict__ bov,
    const float* __restrict__ tau_adp_h1, const float* __restrict__ tau_adp_h2,
    const float* __restrict__ tau_m_h1, const float* __restrict__ tau_m_h2,
    const float* __restrict__ tau_m_o,
    const float* __restrict__ C1, const float* __restrict__ C2,
    float* __restrict__ out)
{
    const int lane = threadIdx.x;
    const int bi = blockIdx.x;
    const unsigned laneOff = lane * 4;
    const unsigned l8 = lane * 8;

    __shared__ __align__(16) unsigned int list1[384], list2[384];

    float4 mem1 = *(const float4*)(mem1_0 + bi * H + laneOff);
    float4 mem2 = *(const float4*)(mem2_0 + bi * H + laneOff);
    float4 b1 = make_float4(0.01f, 0.01f, 0.01f, 0.01f);
    float4 b2 = make_float4(0.01f, 0.01f, 0.01f, 0.01f);
    float4 spk1 = make_float4(0.f, 0.f, 0.f, 0.f);
    float4 spk2 = make_float4(0.f, 0.f, 0.f, 0.f);

    float4 tm1 = *(const float4*)(tau_m_h1 + laneOff);
    float4 ta1 = *(const float4*)(tau_adp_h1 + laneOff);
    float4 tm2 = *(const float4*)(tau_m_h2 + laneOff);
    float4 ta2 = *(const float4*)(tau_adp_h2 + laneOff);
    float4 al1, ro1, al2, ro2;
    al1.x = expf(-1.f / tm1.x); al1.y = expf(-1.f / tm1.y);
    al1.z = expf(-1.f / tm1.z); al1.w = expf(-1.f / tm1.w);
    ro1.x = expf(-1.f / ta1.x); ro1.y = expf(-1.f / ta1.y);
    ro1.z = expf(-1.f / ta1.z); ro1.w = expf(-1.f / ta1.w);
    al2.x = expf(-1.f / tm2.x); al2.y = expf(-1.f / tm2.y);
    al2.z = expf(-1.f / tm2.z); al2.w = expf(-1.f / tm2.w);
    ro2.x = expf(-1.f / ta2.x); ro2.y = expf(-1.f / ta2.y);
    ro2.z = expf(-1.f / ta2.z); ro2.w = expf(-1.f / ta2.w);
    float4 oma1, omr1, oma2, omr2;
    oma1.x = 1.f - al1.x; oma1.y = 1.f - al1.y; oma1.z = 1.f - al1.z; oma1.w = 1.f - al1.w;
    omr1.x = 1.f - ro1.x; omr1.y = 1.f - ro1.y; omr1.z = 1.f - ro1.z; omr1.w = 1.f - ro1.w;
    oma2.x = 1.f - al2.x; oma2.y = 1.f - al2.y; oma2.z = 1.f - al2.z; oma2.w = 1.f - al2.w;
    omr2.x = 1.f - ro2.x; omr2.y = 1.f - ro2.y; omr2.z = 1.f - ro2.z; omr2.w = 1.f - ro2.w;

    float4 b11r = *(const float4*)(b11v + laneOff);
    float4 b12r = *(const float4*)(b12v + laneOff);
    float4 b22r = *(const float4*)(b22v + laneOff);
    float4 bsum2;
    bsum2.x = b12r.x + b22r.x; bsum2.y = b12r.y + b22r.y;
    bsum2.z = b12r.z + b22r.z; bsum2.w = b12r.w + b22r.w;

    float memo = 0.f, alpha_o = 0.f, bo_r = 0.f, accv = 0.f;
    if (lane < D_OUT) {
        memo = memo_0[bi * D_OUT + lane];
        alpha_o = expf(-1.f / tau_m_o[lane]);
        bo_r = bov[lane];
    }

    // carried across steps
    float4 g11c = make_float4(0.f, 0.f, 0.f, 0.f);   // W11 @ sp1(t-1)
    float4 g22c = make_float4(0.f, 0.f, 0.f, 0.f);   // W22 @ sp2(t-1)
    float aOc = 0.f;                                  // Wo  @ sp2(t-1)

    const float* Up = U + (size_t)bi * T * H + laneOff;
    float4 u_cur = *(const float4*)(Up);

    for (int t = 0; t < T; ++t) {
        float4 u_nxt = *(const float4*)(Up + H);   // prefetch (pad row at end)
        Up += H;

        // ---- deferred output for step t-1 (off critical path)
        if (t >= 1) {
            float o = bo_r + aOc;
            memo = memo * alpha_o + (1.f - alpha_o) * o;
            if (t >= 12) {                          // (t-1) > 10
                float e = (lane < D_OUT) ? __expf(memo) : 0.f;
                float s = e;
#pragma unroll
                for (int d = 16; d >= 1; d >>= 1) s += __shfl_xor(s, d, 32);
                if (lane < D_OUT) accv += __fdividef(e, s);
            }
        }

        // ---- layer 1 update (carried g11c, prefetched u_cur)
        float4 h1;
        h1.x = u_cur.x + b11r.x + g11c.x; h1.y = u_cur.y + b11r.y + g11c.y;
        h1.z = u_cur.z + b11r.z + g11c.z; h1.w = u_cur.w + b11r.w + g11c.w;
        b1.x = ro1.x * b1.x + omr1.x * spk1.x; b1.y = ro1.y * b1.y + omr1.y * spk1.y;
        b1.z = ro1.z * b1.z + omr1.z * spk1.z; b1.w = ro1.w * b1.w + omr1.w * spk1.w;
        float B1x = 0.01f + 1.8f * b1.x, B1y = 0.01f + 1.8f * b1.y;
        float B1z = 0.01f + 1.8f * b1.z, B1w = 0.01f + 1.8f * b1.w;
        mem1.x = mem1.x * al1.x + oma1.x * h1.x - B1x * spk1.x;
        mem1.y = mem1.y * al1.y + oma1.y * h1.y - B1y * spk1.y;
        mem1.z = mem1.z * al1.z + oma1.z * h1.z - B1z * spk1.z;
        mem1.w = mem1.w * al1.w + oma1.w * h1.w - B1w * spk1.w;
        spk1.x = (mem1.x - B1x > 0.f) ? 1.f : 0.f;
        spk1.y = (mem1.y - B1y > 0.f) ? 1.f : 0.f;
        spk1.z = (mem1.z - B1z > 0.f) ? 1.f : 0.f;
        spk1.w = (mem1.w - B1w > 0.f) ? 1.f : 0.f;

        int n1 = build_list(list1, lane, spk1.x, spk1.y, spk1.z, spk1.w);
        int n16 = (n1 + 15) & ~15; if (n16 < 16) n16 = 16;
        int nb1 = n16 >> 3;                         // even, >= 2

        v2f g12a = (v2f)(0.f), g12b = (v2f)(0.f);
        v2f g11a = (v2f)(0.f), g11b = (v2f)(0.f);
        gather_c1(list1, nb1, C1, l8, g12a, g12b, g11a, g11b);

        // ---- layer 2 update (fresh g12, carried g22c)
        float4 h2;
        h2.x = bsum2.x + g22c.x + g12a.x; h2.y = bsum2.y + g22c.y + g12a.y;
        h2.z = bsum2.z + g22c.z + g12b.x; h2.w = bsum2.w + g22c.w + g12b.y;
        b2.x = ro2.x * b2.x + omr2.x * spk2.x; b2.y = ro2.y * b2.y + omr2.y * spk2.y;
        b2.z = ro2.z * b2.z + omr2.z * spk2.z; b2.w = ro2.w * b2.w + omr2.w * spk2.w;
        float B2x = 0.01f + 1.8f * b2.x, B2y = 0.01f + 1.8f * b2.y;
        float B2z = 0.01f + 1.8f * b2.z, B2w = 0.01f + 1.8f * b2.w;
        mem2.x = mem2.x * al2.x + oma2.x * h2.x - B2x * spk2.x;
        mem2.y = mem2.y * al2.y + oma2.y * h2.y - B2y * spk2.y;
        mem2.z = mem2.z * al2.z + oma2.z * h2.z - B2z * spk2.z;
        mem2.w = mem2.w * al2.w + oma2.w * h2.w - B2w * spk2.w;
        spk2.x = (mem2.x - B2x > 0.f) ? 1.f : 0.f;
        spk2.y = (mem2.y - B2y > 0.f) ? 1.f : 0.f;
        spk2.z = (mem2.z - B2z > 0.f) ? 1.f : 0.f;
        spk2.w = (mem2.w - B2w > 0.f) ? 1.f : 0.f;

        int n2 = build_list(list2, lane, spk2.x, spk2.y, spk2.z, spk2.w);
        int m16 = (n2 + 15) & ~15; if (m16 < 16) m16 = 16;
        int nb2 = m16 >> 3;

        v2f g22na = (v2f)(0.f), g22nb = (v2f)(0.f);
        float aOn = 0.f;
        gather_c2(list2, nb2, C2, l8, g22na, g22nb, aOn);

        g11c.x = g11a.x; g11c.y = g11a.y; g11c.z = g11b.x; g11c.w = g11b.y;
        g22c.x = g22na.x; g22c.y = g22na.y; g22c.z = g22nb.x; g22c.w = g22nb.y;
        aOc = aOn;
        u_cur = u_nxt;
    }

    // tail: finish memo(T-1) + its softmax term
    {
        float o = bo_r + aOc;
        memo = memo * alpha_o + (1.f - alpha_o) * o;
        float e = (lane < D_OUT) ? __expf(memo) : 0.f;
        float s = e;
#pragma unroll
        for (int d = 16; d >= 1; d >>= 1) s += __shfl_xor(s, d, 32);
        if (lane < D_OUT) accv += __fdividef(e, s);
    }

    if (lane < D_OUT) out[bi * D_OUT + lane] = accv;
}

// ---------------------------------------------------------------------------
extern "C" void kernel_launch(void* const* d_in, const int* in_sizes, int n_in,
                              void* d_out, int out_size, void* d_ws, size_t ws_size,
                              hipStream_t stream) {
    const float* x          = (const float*)d_in[0];
    const float* mem1_0     = (const float*)d_in[1];
    const float* mem2_0     = (const float*)d_in[2];
    const float* memo_0     = (const float*)d_in[3];
    const float* Wi1        = (const float*)d_in[4];
    const float* bi1        = (const float*)d_in[5];
    const float* W11        = (const float*)d_in[6];
    const float* b11        = (const float*)d_in[7];
    const float* W12        = (const float*)d_in[8];
    const float* b12        = (const float*)d_in[9];
    const float* W22        = (const float*)d_in[10];
    const float* b22        = (const float*)d_in[11];
    const float* Wo         = (const float*)d_in[12];
    const float* bo         = (const float*)d_in[13];
    const float* tau_adp_h1 = (const float*)d_in[14];
    const float* tau_adp_h2 = (const float*)d_in[15];
    const float* tau_m_h1   = (const float*)d_in[16];
    const float* tau_m_h2   = (const float*)d_in[17];
    const float* tau_m_o    = (const float*)d_in[18];

    float* U    = (float*)d_ws;                         // [32001][256]
    float* Wi1T = U + ((size_t)BATCH * T + 1) * H;      // [705][256]
    float* C1   = Wi1T + N_WI1T;                        // [257][512]
    float* C2   = C1 + N_C;                             // [257][512]

    int prep_total = N_WI1T + 2 * N_C;
    prep_k<<<(prep_total + 255) / 256, 256, 0, stream>>>(
        Wi1, W11, W12, W22, Wo, Wi1T, C1, C2);

    gemm_u_k<<<(BATCH * T) / GR, 256, 0, stream>>>(x, Wi1T, bi1, U);

    recurrent_k<<<BATCH, 64, 0, stream>>>(U, mem1_0, mem2_0, memo_0,
                                          b11, b12, b22, bo,
                                          tau_adp_h1, tau_adp_h2,
                                          tau_m_h1, tau_m_h2, tau_m_o,
                                          C1, C2, (float*)d_out);
}

// Round 8
// 828.473 us; speedup vs baseline: 2.9910x; 1.0581x over previous
//
#include <hip/hip_runtime.h>
#include <math.h>

#define BATCH 128
#define T 250
#define D_IN 700
#define H 256
#define D_OUT 20

typedef float v2f __attribute__((ext_vector_type(2)));
typedef __attribute__((ext_vector_type(8))) short bf16x8;
typedef __attribute__((ext_vector_type(4))) float f32x4;

static __device__ __forceinline__ unsigned short f2b(float f) {
    unsigned u = __float_as_uint(f);
    u += 0x7FFFu + ((u >> 16) & 1u);
    return (unsigned short)(u >> 16);
}

// ---------------------------------------------------------------------------
// Workspace layout:
//   U     [32001][256] f32   (pad row: u-prefetch overrun at t=249)
//   C1    [257][512] f32     row k, lane l: {W12T[k][4l..4l+3], W11T[k][4l..4l+3]}
//   C2    [257][512] f32     row k, lane l: {W22T[k][4l..4l+3], Wo[l&31][k],0,0,0}
//   Wi1p  [256][704] bf16    cols 700..703 zero (MFMA K-pad)
//   row 256 of C1/C2 is all-zero (spike-list padding target)
// ---------------------------------------------------------------------------
#define N_C  (257 * 512)
#define N_WP (256 * 704)

__global__ void prep_k(const float* __restrict__ Wi1, const float* __restrict__ W11,
                       const float* __restrict__ W12, const float* __restrict__ W22,
                       const float* __restrict__ Wo,
                       unsigned short* __restrict__ Wi1p, float* __restrict__ C1,
                       float* __restrict__ C2) {
    int idx = blockIdx.x * 256 + threadIdx.x;
    if (idx < N_C) {
        int k = idx >> 9, q = idx & 511;
        int l = q >> 3, jj = q & 7;
        float v = 0.f;
        if (k < H) {
            int h = 4 * l + (jj & 3);
            v = (jj < 4) ? W12[h * H + k] : W11[h * H + k];
        }
        C1[idx] = v;
        return;
    }
    idx -= N_C;
    if (idx < N_C) {
        int k = idx >> 9, q = idx & 511;
        int l = q >> 3, jj = q & 7;
        float v = 0.f;
        if (k < H) {
            if (jj < 4) v = W22[(4 * l + jj) * H + k];
            else if (jj == 4 && (l & 31) < D_OUT) v = Wo[(l & 31) * H + k];
        }
        C2[idx] = v;
        return;
    }
    idx -= N_C;
    if (idx < N_WP) {
        int h = idx / 704, k = idx - h * 704;
        Wi1p[idx] = (k < D_IN) ? f2b(Wi1[h * D_IN + k]) : (unsigned short)0;
    }
}

// ---------------------------------------------------------------------------
// U = x @ Wi1^T + bi1 via MFMA 16x16x32 bf16.
// Wave strip = 16 rows x 256 cols (16 C-tiles). Block = 4 waves = 64 rows.
// A: x fp32 loaded + converted in-register (lane m=lane&15, k=quad*8+j).
// B: Wi1p[256][704] bf16, natural row-major = B[k][n] frag layout
//    (lane n=lane&15 reads 8 contiguous k at row n). No LDS, no barriers.
// C/D: col(n)=lane&15, row(m)=quad*4+reg  [HW-verified m89/m91].
// ---------------------------------------------------------------------------
__global__ __launch_bounds__(256) void gemm_u_k(const float* __restrict__ x,
                                                const unsigned short* __restrict__ Wi1p,
                                                const float* __restrict__ bi1,
                                                float* __restrict__ U) {
    const int lane = threadIdx.x & 63;
    const int wv = threadIdx.x >> 6;
    const int quad = lane >> 4;
    const int nl = lane & 15;
    const int mbase = blockIdx.x * 64 + wv * 16;
    const int m = mbase + nl;                 // A-frag row for this lane

    f32x4 acc[16];
#pragma unroll
    for (int i = 0; i < 16; ++i) acc[i] = (f32x4)(0.f);

    // per-lane bias for epilogue: bi1[nt*16 + nl]
    float bias[16];
#pragma unroll
    for (int nt = 0; nt < 16; ++nt) bias[nt] = bi1[nt * 16 + nl];

    const float* xrow = x + (size_t)m * D_IN;
    const unsigned short* brow = Wi1p + nl * 704 + quad * 8;

    for (int k0 = 0; k0 < 704; k0 += 32) {
        int ka = k0 + quad * 8;               // first chunk start, <= 696
        int ka2 = (ka + 4 <= 696) ? ka + 4 : 696;   // clamp overrun (x0 vs pad-0 B)
        float4 q0 = *(const float4*)(xrow + ka);
        float4 q1 = *(const float4*)(xrow + ka2);
        bf16x8 af;
        af[0] = (short)f2b(q0.x); af[1] = (short)f2b(q0.y);
        af[2] = (short)f2b(q0.z); af[3] = (short)f2b(q0.w);
        af[4] = (short)f2b(q1.x); af[5] = (short)f2b(q1.y);
        af[6] = (short)f2b(q1.z); af[7] = (short)f2b(q1.w);

        const unsigned short* bp = brow + k0;
        bf16x8 bf[16];
#pragma unroll
        for (int nt = 0; nt < 16; ++nt)
            bf[nt] = *(const bf16x8*)(bp + nt * 16 * 704);
#pragma unroll
        for (int nt = 0; nt < 16; ++nt)
            acc[nt] = __builtin_amdgcn_mfma_f32_16x16x32_bf16(af, bf[nt], acc[nt], 0, 0, 0);
    }

#pragma unroll
    for (int nt = 0; nt < 16; ++nt) {
#pragma unroll
        for (int r = 0; r < 4; ++r) {
            U[(size_t)(mbase + quad * 4 + r) * H + nt * 16 + nl] = acc[nt][r] + bias[nt];
        }
    }
}

// ---------------------------------------------------------------------------
// Recurrent: one WAVE per batch element — UNCHANGED from R7 (585 us, proven).
// ---------------------------------------------------------------------------

__device__ __forceinline__ int build_list(unsigned int* list, int lane,
                                          float sx, float sy, float sz, float sw) {
    unsigned long long m0 = __ballot(sx > 0.f);
    unsigned long long m1 = __ballot(sy > 0.f);
    unsigned long long m2 = __ballot(sz > 0.f);
    unsigned long long m3 = __ballot(sw > 0.f);
    unsigned long long below = (1ull << lane) - 1ull;
    int c0 = __popcll(m0), c1 = __popcll(m1), c2 = __popcll(m2), c3 = __popcll(m3);
    int n = c0 + c1 + c2 + c3;
    if ((m0 >> lane) & 1) list[__popcll(m0 & below)] = lane * 4;
    if ((m1 >> lane) & 1) list[c0 + __popcll(m1 & below)] = lane * 4 + 1;
    if ((m2 >> lane) & 1) list[c0 + c1 + __popcll(m2 & below)] = lane * 4 + 2;
    if ((m3 >> lane) & 1) list[c0 + c1 + c2 + __popcll(m3 & below)] = lane * 4 + 3;
    list[n + lane] = 256;                   // 64 pad entries -> zero weight row
    __builtin_amdgcn_wave_barrier();
    return n;
}

__device__ __forceinline__ void gather_c1(const unsigned int* lst, int nb,
                                          const float* __restrict__ C,
                                          unsigned l8,
                                          v2f& A0, v2f& A1, v2f& B0, v2f& B1) {
    float4 wa0[8], wb0[8], wa1[8], wb1[8];
    {
        uint4 ia = *(const uint4*)(lst);
        uint4 ib = *(const uint4*)(lst + 4);
        unsigned I[8] = {ia.x, ia.y, ia.z, ia.w, ib.x, ib.y, ib.z, ib.w};
#pragma unroll
        for (int j = 0; j < 8; ++j) {
            const float* p = C + (I[j] << 9) + l8;
            wa0[j] = *(const float4*)(p);
            wb0[j] = *(const float4*)(p + 4);
        }
    }
    {
        uint4 ia = *(const uint4*)(lst + 8);
        uint4 ib = *(const uint4*)(lst + 12);
        unsigned I[8] = {ia.x, ia.y, ia.z, ia.w, ib.x, ib.y, ib.z, ib.w};
#pragma unroll
        for (int j = 0; j < 8; ++j) {
            const float* p = C + (I[j] << 9) + l8;
            wa1[j] = *(const float4*)(p);
            wb1[j] = *(const float4*)(p + 4);
        }
    }
    uint4 p0a = *(const uint4*)(lst + 16);
    uint4 p0b = *(const uint4*)(lst + 20);
    uint4 p1a = *(const uint4*)(lst + 24);
    uint4 p1b = *(const uint4*)(lst + 28);

    for (int b = 2; b < nb; b += 2) {
        {
            unsigned N[8] = {p0a.x, p0a.y, p0a.z, p0a.w, p0b.x, p0b.y, p0b.z, p0b.w};
#pragma unroll
            for (int j = 0; j < 8; ++j) {
                const v2f* w = (const v2f*)&wa0[j];
                A0 += w[0]; A1 += w[1];
                const v2f* v = (const v2f*)&wb0[j];
                B0 += v[0]; B1 += v[1];
                const float* p = C + (N[j] << 9) + l8;
                wa0[j] = *(const float4*)(p);
                wb0[j] = *(const float4*)(p + 4);
            }
            p0a = *(const uint4*)(lst + 8 * b + 16);
            p0b = *(const uint4*)(lst + 8 * b + 20);
        }
        {
            unsigned M[8] = {p1a.x, p1a.y, p1a.z, p1a.w, p1b.x, p1b.y, p1b.z, p1b.w};
#pragma unroll
            for (int j = 0; j < 8; ++j) {
                const v2f* w = (const v2f*)&wa1[j];
                A0 += w[0]; A1 += w[1];
                const v2f* v = (const v2f*)&wb1[j];
                B0 += v[0]; B1 += v[1];
                const float* p = C + (M[j] << 9) + l8;
                wa1[j] = *(const float4*)(p);
                wb1[j] = *(const float4*)(p + 4);
            }
            p1a = *(const uint4*)(lst + 8 * b + 24);
            p1b = *(const uint4*)(lst + 8 * b + 28);
        }
    }
#pragma unroll
    for (int j = 0; j < 8; ++j) {
        const v2f* w = (const v2f*)&wa0[j];
        A0 += w[0]; A1 += w[1];
        const v2f* v = (const v2f*)&wb0[j];
        B0 += v[0]; B1 += v[1];
    }
#pragma unroll
    for (int j = 0; j < 8; ++j) {
        const v2f* w = (const v2f*)&wa1[j];
        A0 += w[0]; A1 += w[1];
        const v2f* v = (const v2f*)&wb1[j];
        B0 += v[0]; B1 += v[1];
    }
}

__device__ __forceinline__ void gather_c2(const unsigned int* lst, int nb,
                                          const float* __restrict__ C,
                                          unsigned l8,
                                          v2f& A0, v2f& A1, float& O) {
    float4 wa0[8], wa1[8]; float o0[8], o1[8];
    {
        uint4 ia = *(const uint4*)(lst);
        uint4 ib = *(const uint4*)(lst + 4);
        unsigned I[8] = {ia.x, ia.y, ia.z, ia.w, ib.x, ib.y, ib.z, ib.w};
#pragma unroll
        for (int j = 0; j < 8; ++j) {
            const float* p = C + (I[j] << 9) + l8;
            wa0[j] = *(const float4*)(p);
            o0[j] = p[4];
        }
    }
    {
        uint4 ia = *(const uint4*)(lst + 8);
        uint4 ib = *(const uint4*)(lst + 12);
        unsigned I[8] = {ia.x, ia.y, ia.z, ia.w, ib.x, ib.y, ib.z, ib.w};
#pragma unroll
        for (int j = 0; j < 8; ++j) {
            const float* p = C + (I[j] << 9) + l8;
            wa1[j] = *(const float4*)(p);
            o1[j] = p[4];
        }
    }
    uint4 p0a = *(const uint4*)(lst + 16);
    uint4 p0b = *(const uint4*)(lst + 20);
    uint4 p1a = *(const uint4*)(lst + 24);
    uint4 p1b = *(const uint4*)(lst + 28);

    for (int b = 2; b < nb; b += 2) {
        {
            unsigned N[8] = {p0a.x, p0a.y, p0a.z, p0a.w, p0b.x, p0b.y, p0b.z, p0b.w};
#pragma unroll
            for (int j = 0; j < 8; ++j) {
                const v2f* w = (const v2f*)&wa0[j];
                A0 += w[0]; A1 += w[1];
                O += o0[j];
                const float* p = C + (N[j] << 9) + l8;
                wa0[j] = *(const float4*)(p);
                o0[j] = p[4];
            }
            p0a = *(const uint4*)(lst + 8 * b + 16);
            p0b = *(const uint4*)(lst + 8 * b + 20);
        }
        {
            unsigned M[8] = {p1a.x, p1a.y, p1a.z, p1a.w, p1b.x, p1b.y, p1b.z, p1b.w};
#pragma unroll
            for (int j = 0; j < 8; ++j) {
                const v2f* w = (const v2f*)&wa1[j];
                A0 += w[0]; A1 += w[1];
                O += o1[j];
                const float* p = C + (M[j] << 9) + l8;
                wa1[j] = *(const float4*)(p);
                o1[j] = p[4];
            }
            p1a = *(const uint4*)(lst + 8 * b + 24);
            p1b = *(const uint4*)(lst + 8 * b + 28);
        }
    }
#pragma unroll
    for (int j = 0; j < 8; ++j) {
        const v2f* w = (const v2f*)&wa0[j];
        A0 += w[0]; A1 += w[1];
        O += o0[j];
    }
#pragma unroll
    for (int j = 0; j < 8; ++j) {
        const v2f* w = (const v2f*)&wa1[j];
        A0 += w[0]; A1 += w[1];
        O += o1[j];
    }
}

__global__ __launch_bounds__(64, 1) void recurrent_k(
    const float* __restrict__ U,
    const float* __restrict__ mem1_0, const float* __restrict__ mem2_0,
    const float* __restrict__ memo_0,
    const float* __restrict__ b11v, const float* __restrict__ b12v,
    const float* __restrict__ b22v, const float* __restrict__ bov,
    const float* __restrict__ tau_adp_h1, const float* __restrict__ tau_adp_h2,
    const float* __restrict__ tau_m_h1, const float* __restrict__ tau_m_h2,
    const float* __restrict__ tau_m_o,
    const float* __restrict__ C1, const float* __restrict__ C2,
    float* __restrict__ out)
{
    const int lane = threadIdx.x;
    const int bi = blockIdx.x;
    const unsigned laneOff = lane * 4;
    const unsigned l8 = lane * 8;

    __shared__ __align__(16) unsigned int list1[384], list2[384];

    float4 mem1 = *(const float4*)(mem1_0 + bi * H + laneOff);
    float4 mem2 = *(const float4*)(mem2_0 + bi * H + laneOff);
    float4 b1 = make_float4(0.01f, 0.01f, 0.01f, 0.01f);
    float4 b2 = make_float4(0.01f, 0.01f, 0.01f, 0.01f);
    float4 spk1 = make_float4(0.f, 0.f, 0.f, 0.f);
    float4 spk2 = make_float4(0.f, 0.f, 0.f, 0.f);

    float4 tm1 = *(const float4*)(tau_m_h1 + laneOff);
    float4 ta1 = *(const float4*)(tau_adp_h1 + laneOff);
    float4 tm2 = *(const float4*)(tau_m_h2 + laneOff);
    float4 ta2 = *(const float4*)(tau_adp_h2 + laneOff);
    float4 al1, ro1, al2, ro2;
    al1.x = expf(-1.f / tm1.x); al1.y = expf(-1.f / tm1.y);
    al1.z = expf(-1.f / tm1.z); al1.w = expf(-1.f / tm1.w);
    ro1.x = expf(-1.f / ta1.x); ro1.y = expf(-1.f / ta1.y);
    ro1.z = expf(-1.f / ta1.z); ro1.w = expf(-1.f / ta1.w);
    al2.x = expf(-1.f / tm2.x); al2.y = expf(-1.f / tm2.y);
    al2.z = expf(-1.f / tm2.z); al2.w = expf(-1.f / tm2.w);
    ro2.x = expf(-1.f / ta2.x); ro2.y = expf(-1.f / ta2.y);
    ro2.z = expf(-1.f / ta2.z); ro2.w = expf(-1.f / ta2.w);
    float4 oma1, omr1, oma2, omr2;
    oma1.x = 1.f - al1.x; oma1.y = 1.f - al1.y; oma1.z = 1.f - al1.z; oma1.w = 1.f - al1.w;
    omr1.x = 1.f - ro1.x; omr1.y = 1.f - ro1.y; omr1.z = 1.f - ro1.z; omr1.w = 1.f - ro1.w;
    oma2.x = 1.f - al2.x; oma2.y = 1.f - al2.y; oma2.z = 1.f - al2.z; oma2.w = 1.f - al2.w;
    omr2.x = 1.f - ro2.x; omr2.y = 1.f - ro2.y; omr2.z = 1.f - ro2.z; omr2.w = 1.f - ro2.w;

    float4 b11r = *(const float4*)(b11v + laneOff);
    float4 b12r = *(const float4*)(b12v + laneOff);
    float4 b22r = *(const float4*)(b22v + laneOff);
    float4 bsum2;
    bsum2.x = b12r.x + b22r.x; bsum2.y = b12r.y + b22r.y;
    bsum2.z = b12r.z + b22r.z; bsum2.w = b12r.w + b22r.w;

    float memo = 0.f, alpha_o = 0.f, bo_r = 0.f, accv = 0.f;
    if (lane < D_OUT) {
        memo = memo_0[bi * D_OUT + lane];
        alpha_o = expf(-1.f / tau_m_o[lane]);
        bo_r = bov[lane];
    }

    float4 g11c = make_float4(0.f, 0.f, 0.f, 0.f);
    float4 g22c = make_float4(0.f, 0.f, 0.f, 0.f);
    float aOc = 0.f;

    const float* Up = U + (size_t)bi * T * H + laneOff;
    float4 u_cur = *(const float4*)(Up);

    for (int t = 0; t < T; ++t) {
        float4 u_nxt = *(const float4*)(Up + H);
        Up += H;

        if (t >= 1) {
            float o = bo_r + aOc;
            memo = memo * alpha_o + (1.f - alpha_o) * o;
            if (t >= 12) {
                float e = (lane < D_OUT) ? __expf(memo) : 0.f;
                float s = e;
#pragma unroll
                for (int d = 16; d >= 1; d >>= 1) s += __shfl_xor(s, d, 32);
                if (lane < D_OUT) accv += __fdividef(e, s);
            }
        }

        float4 h1;
        h1.x = u_cur.x + b11r.x + g11c.x; h1.y = u_cur.y + b11r.y + g11c.y;
        h1.z = u_cur.z + b11r.z + g11c.z; h1.w = u_cur.w + b11r.w + g11c.w;
        b1.x = ro1.x * b1.x + omr1.x * spk1.x; b1.y = ro1.y * b1.y + omr1.y * spk1.y;
        b1.z = ro1.z * b1.z + omr1.z * spk1.z; b1.w = ro1.w * b1.w + omr1.w * spk1.w;
        float B1x = 0.01f + 1.8f * b1.x, B1y = 0.01f + 1.8f * b1.y;
        float B1z = 0.01f + 1.8f * b1.z, B1w = 0.01f + 1.8f * b1.w;
        mem1.x = mem1.x * al1.x + oma1.x * h1.x - B1x * spk1.x;
        mem1.y = mem1.y * al1.y + oma1.y * h1.y - B1y * spk1.y;
        mem1.z = mem1.z * al1.z + oma1.z * h1.z - B1z * spk1.z;
        mem1.w = mem1.w * al1.w + oma1.w * h1.w - B1w * spk1.w;
        spk1.x = (mem1.x - B1x > 0.f) ? 1.f : 0.f;
        spk1.y = (mem1.y - B1y > 0.f) ? 1.f : 0.f;
        spk1.z = (mem1.z - B1z > 0.f) ? 1.f : 0.f;
        spk1.w = (mem1.w - B1w > 0.f) ? 1.f : 0.f;

        int n1 = build_list(list1, lane, spk1.x, spk1.y, spk1.z, spk1.w);
        int n16 = (n1 + 15) & ~15; if (n16 < 16) n16 = 16;
        int nb1 = n16 >> 3;

        v2f g12a = (v2f)(0.f), g12b = (v2f)(0.f);
        v2f g11a = (v2f)(0.f), g11b = (v2f)(0.f);
        gather_c1(list1, nb1, C1, l8, g12a, g12b, g11a, g11b);

        float4 h2;
        h2.x = bsum2.x + g22c.x + g12a.x; h2.y = bsum2.y + g22c.y + g12a.y;
        h2.z = bsum2.z + g22c.z + g12b.x; h2.w = bsum2.w + g22c.w + g12b.y;
        b2.x = ro2.x * b2.x + omr2.x * spk2.x; b2.y = ro2.y * b2.y + omr2.y * spk2.y;
        b2.z = ro2.z * b2.z + omr2.z * spk2.z; b2.w = ro2.w * b2.w + omr2.w * spk2.w;
        float B2x = 0.01f + 1.8f * b2.x, B2y = 0.01f + 1.8f * b2.y;
        float B2z = 0.01f + 1.8f * b2.z, B2w = 0.01f + 1.8f * b2.w;
        mem2.x = mem2.x * al2.x + oma2.x * h2.x - B2x * spk2.x;
        mem2.y = mem2.y * al2.y + oma2.y * h2.y - B2y * spk2.y;
        mem2.z = mem2.z * al2.z + oma2.z * h2.z - B2z * spk2.z;
        mem2.w = mem2.w * al2.w + oma2.w * h2.w - B2w * spk2.w;
        spk2.x = (mem2.x - B2x > 0.f) ? 1.f : 0.f;
        spk2.y = (mem2.y - B2y > 0.f) ? 1.f : 0.f;
        spk2.z = (mem2.z - B2z > 0.f) ? 1.f : 0.f;
        spk2.w = (mem2.w - B2w > 0.f) ? 1.f : 0.f;

        int n2 = build_list(list2, lane, spk2.x, spk2.y, spk2.z, spk2.w);
        int m16 = (n2 + 15) & ~15; if (m16 < 16) m16 = 16;
        int nb2 = m16 >> 3;

        v2f g22na = (v2f)(0.f), g22nb = (v2f)(0.f);
        float aOn = 0.f;
        gather_c2(list2, nb2, C2, l8, g22na, g22nb, aOn);

        g11c.x = g11a.x; g11c.y = g11a.y; g11c.z = g11b.x; g11c.w = g11b.y;
        g22c.x = g22na.x; g22c.y = g22na.y; g22c.z = g22nb.x; g22c.w = g22nb.y;
        aOc = aOn;
        u_cur = u_nxt;
    }

    {
        float o = bo_r + aOc;
        memo = memo * alpha_o + (1.f - alpha_o) * o;
        float e = (lane < D_OUT) ? __expf(memo) : 0.f;
        float s = e;
#pragma unroll
        for (int d = 16; d >= 1; d >>= 1) s += __shfl_xor(s, d, 32);
        if (lane < D_OUT) accv += __fdividef(e, s);
    }

    if (lane < D_OUT) out[bi * D_OUT + lane] = accv;
}

// ---------------------------------------------------------------------------
extern "C" void kernel_launch(void* const* d_in, const int* in_sizes, int n_in,
                              void* d_out, int out_size, void* d_ws, size_t ws_size,
                              hipStream_t stream) {
    const float* x          = (const float*)d_in[0];
    const float* mem1_0     = (const float*)d_in[1];
    const float* mem2_0     = (const float*)d_in[2];
    const float* memo_0     = (const float*)d_in[3];
    const float* Wi1        = (const float*)d_in[4];
    const float* bi1        = (const float*)d_in[5];
    const float* W11        = (const float*)d_in[6];
    const float* b11        = (const float*)d_in[7];
    const float* W12        = (const float*)d_in[8];
    const float* b12        = (const float*)d_in[9];
    const float* W22        = (const float*)d_in[10];
    const float* b22        = (const float*)d_in[11];
    const float* Wo         = (const float*)d_in[12];
    const float* bo         = (const float*)d_in[13];
    const float* tau_adp_h1 = (const float*)d_in[14];
    const float* tau_adp_h2 = (const float*)d_in[15];
    const float* tau_m_h1   = (const float*)d_in[16];
    const float* tau_m_h2   = (const float*)d_in[17];
    const float* tau_m_o    = (const float*)d_in[18];

    float* U = (float*)d_ws;                            // [32001][256] f32
    float* C1 = U + ((size_t)BATCH * T + 1) * H;        // [257][512] f32
    float* C2 = C1 + N_C;                               // [257][512] f32
    unsigned short* Wi1p = (unsigned short*)(C2 + N_C); // [256][704] bf16

    int prep_total = 2 * N_C + N_WP;
    prep_k<<<(prep_total + 255) / 256, 256, 0, stream>>>(
        Wi1, W11, W12, W22, Wo, Wi1p, C1, C2);

    gemm_u_k<<<(BATCH * T) / 64, 256, 0, stream>>>(x, Wi1p, bi1, U);

    recurrent_k<<<BATCH, 64, 0, stream>>>(U, mem1_0, mem2_0, memo_0,
                                          b11, b12, b22, bo,
                                          tau_adp_h1, tau_adp_h2,
                                          tau_m_h1, tau_m_h2, tau_m_o,
                                          C1, C2, (float*)d_out);
}